// Round 5
// baseline (1160.841 us; speedup 1.0000x reference)
//
#include <hip/hip_runtime.h>
#include <math.h>

typedef __bf16 bf16x8 __attribute__((ext_vector_type(8)));
typedef __bf16 bf16x4 __attribute__((ext_vector_type(4)));
typedef float f32x4 __attribute__((ext_vector_type(4)));

#define NTOK 147456
#define LTOK 9216
#define ALPHA 1.8612097182041991f
#define QSCALE 5.656854249492380196f
#define MFMA16(a,b,c) __builtin_amdgcn_mfma_f32_16x16x32_bf16((a),(b),(c),0,0,0)
#define SWB(row,kb) ((kb) ^ ((row)&7))

__device__ __forceinline__ float gelu_tanh(float x) {
    const float u = 0.7978845608028654f * (x + 0.044715f * x * x * x);
    const float e = __expf(2.0f * u);
    const float th = 1.0f - 2.0f / (e + 1.0f);
    return 0.5f * x * (1.0f + th);
}

// ---------------------------------------------------------------------------
// k0: weights -> bf16 transposed [out][k]
// ---------------------------------------------------------------------------
__global__ __launch_bounds__(256) void k0_prep(
    const float* __restrict__ qkv_w, const float* __restrict__ proj_w,
    const float* __restrict__ fc1_w, const float* __restrict__ fc2_w,
    __bf16* __restrict__ qkvT, __bf16* __restrict__ projT,
    __bf16* __restrict__ w1T, __bf16* __restrict__ w2T)
{
    const int id = blockIdx.x * 256 + threadIdx.x;
    if (id < 196608) {
        const int o = id >> 8, k = id & 255;
        qkvT[id] = (__bf16)qkv_w[k * 768 + o];
    } else if (id < 262144) {
        const int i = id - 196608, o = i >> 8, k = i & 255;
        projT[i] = (__bf16)proj_w[k * 256 + o];
    } else if (id < 524288) {
        const int i = id - 262144, o = i >> 8, k = i & 255;
        w1T[i] = (__bf16)fc1_w[k * 1024 + o];
    } else {
        const int i = id - 524288, o = i >> 10, k = i & 1023;
        w2T[i] = (__bf16)fc2_w[k * 256 + o];
    }
}

// ---------------------------------------------------------------------------
// k1a: single-pass QKV GEMM (128x768 per block) with fused shift+window
// gather via LDS srcrow table. grid 1152, block 512 (8 waves, 2x4).
// ---------------------------------------------------------------------------
__global__ __launch_bounds__(512, 2) void k1a_qkv(
    const float* __restrict__ x, const __bf16* __restrict__ qkvT,
    const float* __restrict__ qkv_b, __bf16* __restrict__ qkv)
{
    __shared__ __attribute__((aligned(16))) __bf16 As[128][64];   // 16 KB
    __shared__ __attribute__((aligned(16))) __bf16 Bs[768][64];   // 96 KB
    __shared__ int srcrow[128];
    const int t = threadIdx.x;
    const int wid = t >> 6, lane = t & 63;
    const int l15 = lane & 15, lg = lane >> 4;
    const int mb = blockIdx.x;
    const int wm = wid >> 2, wn = wid & 3;

    // gather table: token index of each A-row (one division chain, once)
    if (t < 128) {
        const int r = mb * 128 + t;
        const int b = r / LTOK, rem = r % LTOK;
        const int w_ = rem / 36, nn = rem % 36;
        const int gh = ((w_ >> 4) * 6 + nn / 6 + 3) % 96;
        const int gw = ((w_ & 15) * 6 + nn % 6 + 3) % 96;
        srcrow[t] = b * LTOK + gh * 96 + gw;
    }

    const f32x4 fzero = {0.f, 0.f, 0.f, 0.f};
    f32x4 acc3[3][4][4];
    #pragma unroll
    for (int nb = 0; nb < 3; ++nb)
        #pragma unroll
        for (int i = 0; i < 4; ++i)
            #pragma unroll
            for (int j = 0; j < 4; ++j) acc3[nb][i][j] = fzero;

    for (int kc = 0; kc < 4; ++kc) {
        __syncthreads();
        // A: 128 rows x 64 k, via table
        #pragma unroll
        for (int o = t; o < 128 * 8; o += 512) {
            const int row = o >> 3, kb = o & 7;
            const float* src = x + (size_t)srcrow[row] * 256 + kc * 64 + kb * 8;
            const float4 f0 = *(const float4*)src;
            const float4 f1 = *(const float4*)(src + 4);
            bf16x8 p;
            p[0] = (__bf16)f0.x; p[1] = (__bf16)f0.y; p[2] = (__bf16)f0.z; p[3] = (__bf16)f0.w;
            p[4] = (__bf16)f1.x; p[5] = (__bf16)f1.y; p[6] = (__bf16)f1.z; p[7] = (__bf16)f1.w;
            *(bf16x8*)&As[row][SWB(row, kb) * 8] = p;
        }
        // B: all 768 out-cols x 64 k
        #pragma unroll
        for (int o = t; o < 768 * 8; o += 512) {
            const int row = o >> 3, kb = o & 7;
            *(uint4*)&Bs[row][SWB(row, kb) * 8] =
                *(const uint4*)(qkvT + (size_t)row * 256 + kc * 64 + kb * 8);
        }
        __syncthreads();
        #pragma unroll
        for (int kk = 0; kk < 2; ++kk) {
            bf16x8 af[4];
            #pragma unroll
            for (int rt = 0; rt < 4; ++rt) {
                const int ar = wm * 64 + rt * 16 + l15;
                af[rt] = *(const bf16x8*)&As[ar][((kk * 4 + lg) ^ (ar & 7)) * 8];
            }
            #pragma unroll
            for (int nb = 0; nb < 3; ++nb) {
                bf16x8 bfr[4];
                #pragma unroll
                for (int ct = 0; ct < 4; ++ct) {
                    const int br = nb * 256 + wn * 64 + ct * 16 + l15;
                    bfr[ct] = *(const bf16x8*)&Bs[br][((kk * 4 + lg) ^ (br & 7)) * 8];
                }
                #pragma unroll
                for (int rt = 0; rt < 4; ++rt)
                    #pragma unroll
                    for (int ct = 0; ct < 4; ++ct)
                        acc3[nb][rt][ct] = MFMA16(af[rt], bfr[ct], acc3[nb][rt][ct]);
            }
        }
    }

    #pragma unroll
    for (int nb = 0; nb < 3; ++nb) {
        const float scale = (nb == 0) ? QSCALE : 1.0f;
        #pragma unroll
        for (int ct = 0; ct < 4; ++ct) {
            const int col = nb * 256 + wn * 64 + ct * 16 + l15;
            const float bias = qkv_b[col];
            #pragma unroll
            for (int rt = 0; rt < 4; ++rt) {
                #pragma unroll
                for (int q = 0; q < 4; ++q) {
                    const int r = mb * 128 + wm * 64 + rt * 16 + lg * 4 + q;
                    qkv[(size_t)r * 768 + col] = (__bf16)((acc3[nb][rt][ct][q] + bias) * scale);
                }
            }
        }
    }
}

// ---------------------------------------------------------------------------
// k1b: per-window MFMA attention. grid 4096, block 256 (4 waves).
// ---------------------------------------------------------------------------
__global__ __launch_bounds__(256) void k1b_attn(
    const __bf16* __restrict__ qkv, const float* __restrict__ bias_table,
    __bf16* __restrict__ attnout)
{
    __shared__ float bias_s[121][8];
    __shared__ __attribute__((aligned(16))) __bf16 P[4][48][64];
    __shared__ __attribute__((aligned(16))) __bf16 vT[4][32][64];

    const int blk = blockIdx.x;
    const int win = blk & 255;
    const int wh = win >> 4, ww = win & 15;
    const int t = threadIdx.x;
    const int wv = t >> 6, lane = t & 63;
    const int l15 = lane & 15, lg = lane >> 4;
    const size_t rowbase = (size_t)blk * 36;

    for (int o = t; o < 968; o += 256) ((float*)bias_s)[o] = bias_table[o];
    const uint4 z4 = {0u, 0u, 0u, 0u};
    for (int o = t; o < 1536; o += 256) ((uint4*)P)[o] = z4;
    for (int o = t; o < 1024; o += 256) ((uint4*)vT)[o] = z4;
    __syncthreads();

    const f32x4 fzero = {0.f, 0.f, 0.f, 0.f};
    int i2_[3], j2_[3], g2_[3];
    #pragma unroll
    for (int ct = 0; ct < 3; ++ct) {
        const int m = ct * 16 + l15;
        const int mm = m < 36 ? m : 35;
        i2_[ct] = mm / 6; j2_[ct] = mm - i2_[ct] * 6;
        const int hg = (wh < 15) ? 0 : (i2_[ct] < 3 ? 1 : 2);
        const int wg = (ww < 15) ? 0 : (j2_[ct] < 3 ? 1 : 2);
        g2_[ct] = hg * 3 + wg;
    }

    for (int hh = 0; hh < 2; ++hh) {
        const int h = hh * 4 + wv;

        bf16x8 aq[3], bk[3];
        #pragma unroll
        for (int rt = 0; rt < 3; ++rt) {
            const int n = rt * 16 + l15;
            const int g = n < 36 ? n : 35;
            const __bf16* p = qkv + (rowbase + g) * 768 + h * 32 + lg * 8;
            aq[rt] = *(const bf16x8*)p;
            bk[rt] = *(const bf16x8*)(p + 256);
            if (n >= 36) {
                bf16x8 z;
                #pragma unroll
                for (int e = 0; e < 8; ++e) z[e] = (__bf16)0.0f;
                bk[rt] = z;
            }
        }

        #pragma unroll
        for (int i = 0; i < 5; ++i) {
            const int idx = i * 64 + lane;
            if (idx < 288) {
                const int m = idx >> 3, d4 = (idx & 7) * 4;
                const bf16x4 vv = *(const bf16x4*)(qkv + (rowbase + m) * 768 + 512 + h * 32 + d4);
                #pragma unroll
                for (int e = 0; e < 4; ++e) {
                    const int d = d4 + e;
                    vT[wv][d][(((m >> 3) ^ (d & 7)) * 8) + (m & 7)] = vv[e];
                }
            }
        }

        f32x4 s[3][3];
        #pragma unroll
        for (int rt = 0; rt < 3; ++rt)
            #pragma unroll
            for (int ct = 0; ct < 3; ++ct)
                s[rt][ct] = MFMA16(aq[rt], bk[ct], fzero);

        float inv_[3][4];
        #pragma unroll
        for (int rt = 0; rt < 3; ++rt) {
            #pragma unroll
            for (int q = 0; q < 4; ++q) {
                const int n0 = rt * 16 + lg * 4 + q;
                const int nn = n0 < 36 ? n0 : 35;
                const int i1 = nn / 6, j1 = nn - i1 * 6;
                const int hg1 = (wh < 15) ? 0 : (i1 < 3 ? 1 : 2);
                const int wg1 = (ww < 15) ? 0 : (j1 < 3 ? 1 : 2);
                const int g1 = hg1 * 3 + wg1;
                #pragma unroll
                for (int ct = 0; ct < 3; ++ct) {
                    const int m = ct * 16 + l15;
                    float val;
                    if (m < 36) {
                        val = s[rt][ct][q] + bias_s[(i1 - i2_[ct] + 5) * 11 + (j1 - j2_[ct] + 5)][h];
                        if (g1 != g2_[ct]) val -= 100.0f;
                    } else {
                        val = -1e30f;
                    }
                    s[rt][ct][q] = val;
                }
                float mx = fmaxf(fmaxf(s[rt][0][q], s[rt][1][q]), s[rt][2][q]);
                mx = fmaxf(mx, __shfl_xor(mx, 1, 16));
                mx = fmaxf(mx, __shfl_xor(mx, 2, 16));
                mx = fmaxf(mx, __shfl_xor(mx, 4, 16));
                mx = fmaxf(mx, __shfl_xor(mx, 8, 16));
                float sum = 0.f;
                #pragma unroll
                for (int ct = 0; ct < 3; ++ct) {
                    const float e = __expf(s[rt][ct][q] - mx);
                    s[rt][ct][q] = e;
                    sum += e;
                }
                sum += __shfl_xor(sum, 1, 16);
                sum += __shfl_xor(sum, 2, 16);
                sum += __shfl_xor(sum, 4, 16);
                sum += __shfl_xor(sum, 8, 16);
                inv_[rt][q] = 1.0f / sum;
            }
        }

        #pragma unroll
        for (int rt = 0; rt < 3; ++rt)
            #pragma unroll
            for (int q = 0; q < 4; ++q) {
                const int row = rt * 16 + lg * 4 + q;
                #pragma unroll
                for (int ct = 0; ct < 3; ++ct) {
                    const int m = ct * 16 + l15;
                    P[wv][row][(((m >> 3) ^ (row & 7)) * 8) + (m & 7)] = (__bf16)s[rt][ct][q];
                }
            }
        __syncthreads();

        f32x4 ov[3][2];
        #pragma unroll
        for (int rt = 0; rt < 3; ++rt)
            #pragma unroll
            for (int cd = 0; cd < 2; ++cd) ov[rt][cd] = fzero;
        #pragma unroll
        for (int kk = 0; kk < 2; ++kk) {
            bf16x8 pa[3], bv[2];
            #pragma unroll
            for (int rt = 0; rt < 3; ++rt) {
                const int ar = rt * 16 + l15;
                pa[rt] = *(const bf16x8*)&P[wv][ar][((kk * 4 + lg) ^ (ar & 7)) * 8];
            }
            #pragma unroll
            for (int cd = 0; cd < 2; ++cd) {
                const int d = cd * 16 + l15;
                bv[cd] = *(const bf16x8*)&vT[wv][d][((kk * 4 + lg) ^ (d & 7)) * 8];
            }
            #pragma unroll
            for (int rt = 0; rt < 3; ++rt)
                #pragma unroll
                for (int cd = 0; cd < 2; ++cd)
                    ov[rt][cd] = MFMA16(pa[rt], bv[cd], ov[rt][cd]);
        }

        #pragma unroll
        for (int rt = 0; rt < 3; ++rt)
            #pragma unroll
            for (int cd = 0; cd < 2; ++cd)
                #pragma unroll
                for (int q = 0; q < 4; ++q) {
                    const int n = rt * 16 + lg * 4 + q;
                    if (n < 36)
                        attnout[(rowbase + n) * 256 + h * 32 + cd * 16 + l15] =
                            (__bf16)(ov[rt][cd][q] * inv_[rt][q]);
                }
        __syncthreads();
    }
}

// ---------------------------------------------------------------------------
// k2: MFMA proj (BM=128, 4x4 wave tiles) + roll permute + residual + LN1 -> x1
// grid 1152, block 512
// ---------------------------------------------------------------------------
__global__ __launch_bounds__(512) void k2_proj_ln(
    const __bf16* __restrict__ attnout, const __bf16* __restrict__ projT,
    const float* __restrict__ proj_b, const float* __restrict__ x,
    const float* __restrict__ n1w, const float* __restrict__ n1b,
    float* __restrict__ x1)
{
    __shared__ __attribute__((aligned(16))) __bf16 As[128][64];
    __shared__ __attribute__((aligned(16))) __bf16 Bs[256][64];
    __shared__ float ps[128][4], ps2[128][4];
    const int t = threadIdx.x;
    const int wid = t >> 6, lane = t & 63;
    const int l15 = lane & 15, lg = lane >> 4;
    const int mb = blockIdx.x;
    const int wm = wid >> 2, wn = wid & 3;

    const f32x4 fzero = {0.f, 0.f, 0.f, 0.f};
    f32x4 acc[4][4];
    #pragma unroll
    for (int i = 0; i < 4; ++i)
        #pragma unroll
        for (int j = 0; j < 4; ++j) acc[i][j] = fzero;

    for (int kc = 0; kc < 4; ++kc) {
        __syncthreads();
        for (int o = t; o < 128 * 8; o += 512) {
            const int row = o >> 3, kb = o & 7;
            *(uint4*)&As[row][SWB(row, kb) * 8] =
                *(const uint4*)(attnout + (size_t)(mb * 128 + row) * 256 + kc * 64 + kb * 8);
        }
        for (int o = t; o < 256 * 8; o += 512) {
            const int row = o >> 3, kb = o & 7;
            *(uint4*)&Bs[row][SWB(row, kb) * 8] =
                *(const uint4*)(projT + (size_t)row * 256 + kc * 64 + kb * 8);
        }
        __syncthreads();
        #pragma unroll
        for (int kk = 0; kk < 2; ++kk) {
            bf16x8 af[4], bfr[4];
            #pragma unroll
            for (int rt = 0; rt < 4; ++rt) {
                const int ar = wm * 64 + rt * 16 + l15;
                af[rt] = *(const bf16x8*)&As[ar][((kk * 4 + lg) ^ (ar & 7)) * 8];
            }
            #pragma unroll
            for (int ct = 0; ct < 4; ++ct) {
                const int br = wn * 64 + ct * 16 + l15;
                bfr[ct] = *(const bf16x8*)&Bs[br][((kk * 4 + lg) ^ (br & 7)) * 8];
            }
            #pragma unroll
            for (int rt = 0; rt < 4; ++rt)
                #pragma unroll
                for (int ct = 0; ct < 4; ++ct)
                    acc[rt][ct] = MFMA16(af[rt], bfr[ct], acc[rt][ct]);
        }
    }

    int dtok_[4][4];
    #pragma unroll
    for (int rt = 0; rt < 4; ++rt) {
        #pragma unroll
        for (int q = 0; q < 4; ++q) {
            const int rowl = wm * 64 + rt * 16 + lg * 4 + q;
            const int tok = mb * 128 + rowl;
            const int b = tok / LTOK, l = tok % LTOK;
            const int hh = l / 96, wwp = l % 96;
            const int dtok = b * LTOK + ((hh + 3) % 96) * 96 + ((wwp + 3) % 96);
            dtok_[rt][q] = dtok;
            float s = 0.f, s2 = 0.f;
            #pragma unroll
            for (int ct = 0; ct < 4; ++ct) {
                const int col = wn * 64 + ct * 16 + l15;
                const float v = acc[rt][ct][q] + proj_b[col] + ALPHA * x[(size_t)dtok * 256 + col];
                acc[rt][ct][q] = v;
                s += v; s2 += v * v;
            }
            s  += __shfl_xor(s, 1, 16);  s += __shfl_xor(s, 2, 16);
            s  += __shfl_xor(s, 4, 16);  s += __shfl_xor(s, 8, 16);
            s2 += __shfl_xor(s2, 1, 16); s2 += __shfl_xor(s2, 2, 16);
            s2 += __shfl_xor(s2, 4, 16); s2 += __shfl_xor(s2, 8, 16);
            if (l15 == 0) { ps[rowl][wn] = s; ps2[rowl][wn] = s2; }
        }
    }
    __syncthreads();
    #pragma unroll
    for (int rt = 0; rt < 4; ++rt) {
        #pragma unroll
        for (int q = 0; q < 4; ++q) {
            const int rowl = wm * 64 + rt * 16 + lg * 4 + q;
            const float S  = ps[rowl][0] + ps[rowl][1] + ps[rowl][2] + ps[rowl][3];
            const float S2 = ps2[rowl][0] + ps2[rowl][1] + ps2[rowl][2] + ps2[rowl][3];
            const float mu = S * (1.0f / 256.0f);
            const float var = S2 * (1.0f / 256.0f) - mu * mu;
            const float rstd = rsqrtf(var + 1e-5f);
            float* op = x1 + (size_t)dtok_[rt][q] * 256;
            #pragma unroll
            for (int ct = 0; ct < 4; ++ct) {
                const int col = wn * 64 + ct * 16 + l15;
                op[col] = (acc[rt][ct][q] - mu) * rstd * n1w[col] + n1b[col];
            }
        }
    }
}

// ---------------------------------------------------------------------------
// k3a: fc1 + GELU -> hmid bf16 (one token half). grid (576,4), block 512
// ---------------------------------------------------------------------------
__global__ __launch_bounds__(512) void k3a_fc1(
    const float* __restrict__ x1, const __bf16* __restrict__ w1T,
    const float* __restrict__ fc1_b, __bf16* __restrict__ hmid, int row0)
{
    __shared__ __attribute__((aligned(16))) __bf16 As[128][64];
    __shared__ __attribute__((aligned(16))) __bf16 Bs[256][64];
    const int t = threadIdx.x;
    const int wid = t >> 6, lane = t & 63;
    const int l15 = lane & 15, lg = lane >> 4;
    const int mb = blockIdx.x, nb = blockIdx.y;
    const int wm = wid >> 2, wn = wid & 3;

    const f32x4 fzero = {0.f, 0.f, 0.f, 0.f};
    f32x4 acc[4][4];
    #pragma unroll
    for (int i = 0; i < 4; ++i)
        #pragma unroll
        for (int j = 0; j < 4; ++j) acc[i][j] = fzero;

    for (int kc = 0; kc < 4; ++kc) {
        __syncthreads();
        for (int o = t; o < 128 * 8; o += 512) {
            const int row = o >> 3, kb = o & 7;
            const float* src = x1 + (size_t)(row0 + mb * 128 + row) * 256 + kc * 64 + kb * 8;
            const float4 f0 = *(const float4*)src;
            const float4 f1 = *(const float4*)(src + 4);
            bf16x8 p;
            p[0] = (__bf16)f0.x; p[1] = (__bf16)f0.y; p[2] = (__bf16)f0.z; p[3] = (__bf16)f0.w;
            p[4] = (__bf16)f1.x; p[5] = (__bf16)f1.y; p[6] = (__bf16)f1.z; p[7] = (__bf16)f1.w;
            *(bf16x8*)&As[row][SWB(row, kb) * 8] = p;
        }
        for (int o = t; o < 256 * 8; o += 512) {
            const int row = o >> 3, kb = o & 7;
            *(uint4*)&Bs[row][SWB(row, kb) * 8] =
                *(const uint4*)(w1T + (size_t)(nb * 256 + row) * 256 + kc * 64 + kb * 8);
        }
        __syncthreads();
        #pragma unroll
        for (int kk = 0; kk < 2; ++kk) {
            bf16x8 af[4], bfr[4];
            #pragma unroll
            for (int rt = 0; rt < 4; ++rt) {
                const int ar = wm * 64 + rt * 16 + l15;
                af[rt] = *(const bf16x8*)&As[ar][((kk * 4 + lg) ^ (ar & 7)) * 8];
            }
            #pragma unroll
            for (int ct = 0; ct < 4; ++ct) {
                const int br = wn * 64 + ct * 16 + l15;
                bfr[ct] = *(const bf16x8*)&Bs[br][((kk * 4 + lg) ^ (br & 7)) * 8];
            }
            #pragma unroll
            for (int rt = 0; rt < 4; ++rt)
                #pragma unroll
                for (int ct = 0; ct < 4; ++ct)
                    acc[rt][ct] = MFMA16(af[rt], bfr[ct], acc[rt][ct]);
        }
    }

    #pragma unroll
    for (int ct = 0; ct < 4; ++ct) {
        const int col = nb * 256 + wn * 64 + ct * 16 + l15;
        const float b1 = fc1_b[col];
        #pragma unroll
        for (int rt = 0; rt < 4; ++rt) {
            #pragma unroll
            for (int q = 0; q < 4; ++q) {
                const int rowl = mb * 128 + wm * 64 + rt * 16 + lg * 4 + q;
                hmid[(size_t)rowl * 1024 + col] = (__bf16)gelu_tanh(acc[rt][ct][q] + b1);
            }
        }
    }
}

// ---------------------------------------------------------------------------
// k3b: fc2 + residual + LN2 -> out (one token half). grid 576, block 512
// ---------------------------------------------------------------------------
__global__ __launch_bounds__(512) void k3b_fc2(
    const __bf16* __restrict__ hmid, const __bf16* __restrict__ w2T,
    const float* __restrict__ fc2_b, const float* __restrict__ x1,
    const float* __restrict__ n2w, const float* __restrict__ n2b,
    float* __restrict__ out, int row0)
{
    __shared__ __attribute__((aligned(16))) __bf16 As[128][64];
    __shared__ __attribute__((aligned(16))) __bf16 Bs[256][64];
    __shared__ float ps[128][4], ps2[128][4];
    const int t = threadIdx.x;
    const int wid = t >> 6, lane = t & 63;
    const int l15 = lane & 15, lg = lane >> 4;
    const int mb = blockIdx.x;
    const int wm = wid >> 2, wn = wid & 3;

    const f32x4 fzero = {0.f, 0.f, 0.f, 0.f};
    f32x4 acc[4][4];
    #pragma unroll
    for (int i = 0; i < 4; ++i)
        #pragma unroll
        for (int j = 0; j < 4; ++j) acc[i][j] = fzero;

    for (int kc = 0; kc < 16; ++kc) {
        __syncthreads();
        for (int o = t; o < 128 * 8; o += 512) {
            const int row = o >> 3, kb = o & 7;
            *(uint4*)&As[row][SWB(row, kb) * 8] =
                *(const uint4*)(hmid + (size_t)(mb * 128 + row) * 1024 + kc * 64 + kb * 8);
        }
        for (int o = t; o < 256 * 8; o += 512) {
            const int row = o >> 3, kb = o & 7;
            *(uint4*)&Bs[row][SWB(row, kb) * 8] =
                *(const uint4*)(w2T + (size_t)row * 1024 + kc * 64 + kb * 8);
        }
        __syncthreads();
        #pragma unroll
        for (int kk = 0; kk < 2; ++kk) {
            bf16x8 af[4], bfr[4];
            #pragma unroll
            for (int rt = 0; rt < 4; ++rt) {
                const int ar = wm * 64 + rt * 16 + l15;
                af[rt] = *(const bf16x8*)&As[ar][((kk * 4 + lg) ^ (ar & 7)) * 8];
            }
            #pragma unroll
            for (int ct = 0; ct < 4; ++ct) {
                const int br = wn * 64 + ct * 16 + l15;
                bfr[ct] = *(const bf16x8*)&Bs[br][((kk * 4 + lg) ^ (br & 7)) * 8];
            }
            #pragma unroll
            for (int rt = 0; rt < 4; ++rt)
                #pragma unroll
                for (int ct = 0; ct < 4; ++ct)
                    acc[rt][ct] = MFMA16(af[rt], bfr[ct], acc[rt][ct]);
        }
    }

    #pragma unroll
    for (int rt = 0; rt < 4; ++rt) {
        #pragma unroll
        for (int q = 0; q < 4; ++q) {
            const int rowl = wm * 64 + rt * 16 + lg * 4 + q;
            const size_t tok = (size_t)(row0 + mb * 128 + rowl);
            float s = 0.f, s2 = 0.f;
            #pragma unroll
            for (int ct = 0; ct < 4; ++ct) {
                const int col = wn * 64 + ct * 16 + l15;
                const float v = acc[rt][ct][q] + fc2_b[col] + ALPHA * x1[tok * 256 + col];
                acc[rt][ct][q] = v;
                s += v; s2 += v * v;
            }
            s  += __shfl_xor(s, 1, 16);  s += __shfl_xor(s, 2, 16);
            s  += __shfl_xor(s, 4, 16);  s += __shfl_xor(s, 8, 16);
            s2 += __shfl_xor(s2, 1, 16); s2 += __shfl_xor(s2, 2, 16);
            s2 += __shfl_xor(s2, 4, 16); s2 += __shfl_xor(s2, 8, 16);
            if (l15 == 0) { ps[rowl][wn] = s; ps2[rowl][wn] = s2; }
        }
    }
    __syncthreads();
    #pragma unroll
    for (int rt = 0; rt < 4; ++rt) {
        #pragma unroll
        for (int q = 0; q < 4; ++q) {
            const int rowl = wm * 64 + rt * 16 + lg * 4 + q;
            const size_t tok = (size_t)(row0 + mb * 128 + rowl);
            const float S  = ps[rowl][0] + ps[rowl][1] + ps[rowl][2] + ps[rowl][3];
            const float S2 = ps2[rowl][0] + ps2[rowl][1] + ps2[rowl][2] + ps2[rowl][3];
            const float mu = S * (1.0f / 256.0f);
            const float var = S2 * (1.0f / 256.0f) - mu * mu;
            const float rstd = rsqrtf(var + 1e-5f);
            float* op = out + tok * 256;
            #pragma unroll
            for (int ct = 0; ct < 4; ++ct) {
                const int col = wn * 64 + ct * 16 + l15;
                op[col] = (acc[rt][ct][q] - mu) * rstd * n2w[col] + n2b[col];
            }
        }
    }
}

// ---------------------------------------------------------------------------
extern "C" void kernel_launch(void* const* d_in, const int* in_sizes, int n_in,
                              void* d_out, int out_size, void* d_ws, size_t ws_size,
                              hipStream_t stream)
{
    const float* x          = (const float*)d_in[0];
    const float* qkv_w      = (const float*)d_in[1];
    const float* qkv_b      = (const float*)d_in[2];
    const float* bias_table = (const float*)d_in[3];
    const float* proj_w     = (const float*)d_in[4];
    const float* proj_b     = (const float*)d_in[5];
    const float* n1w        = (const float*)d_in[6];
    const float* n1b        = (const float*)d_in[7];
    const float* n2w        = (const float*)d_in[8];
    const float* n2b        = (const float*)d_in[9];
    const float* fc1_w      = (const float*)d_in[10];
    const float* fc1_b      = (const float*)d_in[11];
    const float* fc2_w      = (const float*)d_in[12];
    const float* fc2_b      = (const float*)d_in[13];
    float* out = (float*)d_out;

    // ws layout (bytes), total 303,562,752:
    //   [0,          226492416)  qkv bf16            (dead after k1b)
    //   [0,          150994944)  x1 fp32             (overlays dead qkv)
    //   [150994944,  301989888)  hmid bf16, one half (overlays dead qkv tail + attnout)
    //   [226492416,  301989888)  attnout bf16        (dead after k2)
    //   [301989888,  303562752)  weight tables
    char* ws = (char*)d_ws;
    __bf16* qkv     = (__bf16*)ws;
    float*  x1      = (float*)ws;
    __bf16* hmid    = (__bf16*)(ws + 150994944);
    __bf16* attnout = (__bf16*)(ws + 226492416);
    __bf16* qkvT    = (__bf16*)(ws + 301989888);
    __bf16* projT   = (__bf16*)(ws + 302383104);
    __bf16* w1T     = (__bf16*)(ws + 302514176);
    __bf16* w2T     = (__bf16*)(ws + 303038464);

    k0_prep<<<3072, 256, 0, stream>>>(qkv_w, proj_w, fc1_w, fc2_w, qkvT, projT, w1T, w2T);
    k1a_qkv<<<1152, 512, 0, stream>>>(x, qkvT, qkv_b, qkv);
    k1b_attn<<<4096, 256, 0, stream>>>(qkv, bias_table, attnout);
    k2_proj_ln<<<1152, 512, 0, stream>>>(attnout, projT, proj_b, x, n1w, n1b, x1);
    for (int h = 0; h < 2; ++h) {
        k3a_fc1<<<dim3(576, 4), 512, 0, stream>>>(x1, w1T, fc1_b, hmid, h * 73728);
        k3b_fc2<<<576, 512, 0, stream>>>(hmid, w2T, fc2_b, x1, n2w, n2b, out, h * 73728);
    }
}

// Round 6
// 1074.615 us; speedup vs baseline: 1.0802x; 1.0802x over previous
//
#include <hip/hip_runtime.h>
#include <math.h>

typedef __bf16 bf16x8 __attribute__((ext_vector_type(8)));
typedef float f32x4 __attribute__((ext_vector_type(4)));

#define NTOK 147456
#define LTOK 9216
#define ALPHA 1.8612097182041991f
#define QSCALE 5.656854249492380196f
#define MFMA16(a,b,c) __builtin_amdgcn_mfma_f32_16x16x32_bf16((a),(b),(c),0,0,0)
#define SWB(row,kb) ((kb) ^ ((row)&7))

__device__ __forceinline__ float gelu_tanh(float x) {
    const float u = 0.7978845608028654f * (x + 0.044715f * x * x * x);
    const float e = __expf(2.0f * u);
    const float th = 1.0f - 2.0f / (e + 1.0f);
    return 0.5f * x * (1.0f + th);
}

// ---------------------------------------------------------------------------
// k0: weights -> bf16 transposed [out][k]
// ---------------------------------------------------------------------------
__global__ __launch_bounds__(256) void k0_prep(
    const float* __restrict__ qkv_w, const float* __restrict__ proj_w,
    const float* __restrict__ fc1_w, const float* __restrict__ fc2_w,
    __bf16* __restrict__ qkvT, __bf16* __restrict__ projT,
    __bf16* __restrict__ w1T, __bf16* __restrict__ w2T)
{
    const int id = blockIdx.x * 256 + threadIdx.x;
    if (id < 196608) {
        const int o = id >> 8, k = id & 255;
        qkvT[id] = (__bf16)qkv_w[k * 768 + o];
    } else if (id < 262144) {
        const int i = id - 196608, o = i >> 8, k = i & 255;
        projT[i] = (__bf16)proj_w[k * 256 + o];
    } else if (id < 524288) {
        const int i = id - 262144, o = i >> 8, k = i & 255;
        w1T[i] = (__bf16)fc1_w[k * 1024 + o];
    } else {
        const int i = id - 524288, o = i >> 10, k = i & 1023;
        w2T[i] = (__bf16)fc2_w[k * 256 + o];
    }
}

// ---------------------------------------------------------------------------
// k1f: FUSED QKV GEMM + window attention.
// Block = 2 padded windows (96 rows, 48/window, real 36). 8 waves (2 wm x 4 wn):
// wave (wm,wn) owns window (2*mb+wm), heads {2wn, 2wn+1}. grid 2048, block 512.
// LDS: GEMM As[96][64]+Bs[768][64]; attn reuses Bs as 8x12KB wave slabs.
// ---------------------------------------------------------------------------
__global__ __launch_bounds__(512) void k1f_qkv_attn(
    const float* __restrict__ x, const __bf16* __restrict__ qkvT,
    const float* __restrict__ qkv_b, const float* __restrict__ bias_table,
    __bf16* __restrict__ attnout)
{
    __shared__ __attribute__((aligned(16))) char SM[114944];
    typedef __bf16 (*lds64_t)[64];
    lds64_t As = (lds64_t)SM;                        // [96][64]  12288 B
    lds64_t Bs = (lds64_t)(SM + 12288);              // [768][64] 98304 B
    int*   srcrow = (int*)(SM + 110592);             // 96 ints
    float* bias_s = (float*)(SM + 110976);           // 968 floats

    const int t = threadIdx.x;
    const int wid = t >> 6, lane = t & 63;
    const int l15 = lane & 15, lg = lane >> 4;
    const int mb = blockIdx.x;
    const int wm = wid >> 2, wn = wid & 3;

    // wave-private attn slabs carved from Bs region
    lds64_t slQ = (lds64_t)(SM + 12288 + wid * 12288);          // [48][64]
    lds64_t slK = (lds64_t)(SM + 12288 + wid * 12288 + 6144);   // [48][64] (P later)

    // gather table for 96 padded rows (2 windows x 48, clamp n>35 -> 35)
    if (t < 96) {
        const int wloc = (t >= 48) ? 1 : 0;
        int n = t - wloc * 48;
        if (n > 35) n = 35;
        const int wndw = 2 * mb + wloc;
        const int b = wndw >> 8, win = wndw & 255;
        const int wh = win >> 4, ww = win & 15;
        const int gh = (wh * 6 + n / 6 + 3) % 96;
        const int gw = (ww * 6 + n % 6 + 3) % 96;
        srcrow[t] = b * LTOK + gh * 96 + gw;
    }
    for (int o = t; o < 968; o += 512) bias_s[o] = bias_table[o];

    const f32x4 fzero = {0.f, 0.f, 0.f, 0.f};
    f32x4 acc3[3][3][4];
    #pragma unroll
    for (int nb = 0; nb < 3; ++nb)
        #pragma unroll
        for (int i = 0; i < 3; ++i)
            #pragma unroll
            for (int j = 0; j < 4; ++j) acc3[nb][i][j] = fzero;

    // ---- QKV GEMM: 96 x 768, K=256 ----
    for (int kc = 0; kc < 4; ++kc) {
        __syncthreads();
        for (int o = t; o < 96 * 8; o += 512) {
            const int row = o >> 3, kb = o & 7;
            const float* src = x + (size_t)srcrow[row] * 256 + kc * 64 + kb * 8;
            const float4 f0 = *(const float4*)src;
            const float4 f1 = *(const float4*)(src + 4);
            bf16x8 p;
            p[0] = (__bf16)f0.x; p[1] = (__bf16)f0.y; p[2] = (__bf16)f0.z; p[3] = (__bf16)f0.w;
            p[4] = (__bf16)f1.x; p[5] = (__bf16)f1.y; p[6] = (__bf16)f1.z; p[7] = (__bf16)f1.w;
            *(bf16x8*)&As[row][SWB(row, kb) * 8] = p;
        }
        for (int o = t; o < 768 * 8; o += 512) {
            const int row = o >> 3, kb = o & 7;
            *(uint4*)&Bs[row][SWB(row, kb) * 8] =
                *(const uint4*)(qkvT + (size_t)row * 256 + kc * 64 + kb * 8);
        }
        __syncthreads();
        #pragma unroll
        for (int kk = 0; kk < 2; ++kk) {
            bf16x8 af[3];
            #pragma unroll
            for (int rt = 0; rt < 3; ++rt) {
                const int ar = wm * 48 + rt * 16 + l15;
                af[rt] = *(const bf16x8*)&As[ar][((kk * 4 + lg) ^ (ar & 7)) * 8];
            }
            #pragma unroll
            for (int nb = 0; nb < 3; ++nb) {
                bf16x8 bfr[4];
                #pragma unroll
                for (int ct = 0; ct < 4; ++ct) {
                    const int br = nb * 256 + wn * 64 + ct * 16 + l15;
                    bfr[ct] = *(const bf16x8*)&Bs[br][((kk * 4 + lg) ^ (br & 7)) * 8];
                }
                #pragma unroll
                for (int rt = 0; rt < 3; ++rt)
                    #pragma unroll
                    for (int ct = 0; ct < 4; ++ct)
                        acc3[nb][rt][ct] = MFMA16(af[rt], bfr[ct], acc3[nb][rt][ct]);
            }
        }
    }
    __syncthreads();   // all Bs reads done; slabs may be written

    // ---- stage Q (scaled+bias) and K (+bias) into wave slab ----
    #pragma unroll
    for (int ct = 0; ct < 4; ++ct) {
        const int dq = ct * 16 + l15;   // 0..63 local d (head pair)
        const float qb  = qkv_b[wn * 64 + dq];
        const float kb2 = qkv_b[256 + wn * 64 + dq];
        #pragma unroll
        for (int rt = 0; rt < 3; ++rt) {
            #pragma unroll
            for (int q = 0; q < 4; ++q) {
                const int tok = rt * 16 + lg * 4 + q;  // 0..47
                const int off = (((dq >> 3) ^ (tok & 7)) * 8) + (dq & 7);
                slQ[tok][off] = (__bf16)((acc3[0][rt][ct][q] + qb) * QSCALE);
                slK[tok][off] = (__bf16)(acc3[1][rt][ct][q] + kb2);
            }
        }
    }
    __syncthreads();

    // window/mask constants for this wave's window
    const int wndw = 2 * mb + wm;
    const int win = wndw & 255;
    const int wh = win >> 4, ww = win & 15;
    const size_t rowbase = (size_t)wndw * 36;
    int i2_[3], j2_[3], g2_[3];
    #pragma unroll
    for (int ct = 0; ct < 3; ++ct) {
        const int m = ct * 16 + l15;
        const int mm = m < 36 ? m : 35;
        i2_[ct] = mm / 6; j2_[ct] = mm - i2_[ct] * 6;
        const int hg = (wh < 15) ? 0 : (i2_[ct] < 3 ? 1 : 2);
        const int wg = (ww < 15) ? 0 : (j2_[ct] < 3 ? 1 : 2);
        g2_[ct] = hg * 3 + wg;
    }

    // ---- S = Q K^T for both heads, softmax in-register ----
    f32x4 sh[2][3][3];
    float inv_[2][3][4];
    #pragma unroll
    for (int hh = 0; hh < 2; ++hh) {
        const int h = wn * 2 + hh;
        bf16x8 aq[3], bk[3];
        #pragma unroll
        for (int rt = 0; rt < 3; ++rt) {
            const int ar = rt * 16 + l15;
            aq[rt] = *(const bf16x8*)&slQ[ar][((hh * 4 + lg) ^ (ar & 7)) * 8];
            bk[rt] = *(const bf16x8*)&slK[ar][((hh * 4 + lg) ^ (ar & 7)) * 8];
        }
        #pragma unroll
        for (int rt = 0; rt < 3; ++rt)
            #pragma unroll
            for (int ct = 0; ct < 3; ++ct)
                sh[hh][rt][ct] = MFMA16(aq[rt], bk[ct], fzero);

        #pragma unroll
        for (int rt = 0; rt < 3; ++rt) {
            #pragma unroll
            for (int q = 0; q < 4; ++q) {
                const int n0 = rt * 16 + lg * 4 + q;
                const int nn = n0 < 36 ? n0 : 35;
                const int i1 = nn / 6, j1 = nn - i1 * 6;
                const int hg1 = (wh < 15) ? 0 : (i1 < 3 ? 1 : 2);
                const int wg1 = (ww < 15) ? 0 : (j1 < 3 ? 1 : 2);
                const int g1 = hg1 * 3 + wg1;
                #pragma unroll
                for (int ct = 0; ct < 3; ++ct) {
                    const int m = ct * 16 + l15;
                    float val;
                    if (m < 36) {
                        val = sh[hh][rt][ct][q] + bias_s[((i1 - i2_[ct] + 5) * 11 + (j1 - j2_[ct] + 5)) * 8 + h];
                        if (g1 != g2_[ct]) val -= 100.0f;
                    } else {
                        val = -1e30f;
                    }
                    sh[hh][rt][ct][q] = val;
                }
                float mx = fmaxf(fmaxf(sh[hh][rt][0][q], sh[hh][rt][1][q]), sh[hh][rt][2][q]);
                mx = fmaxf(mx, __shfl_xor(mx, 1, 16));
                mx = fmaxf(mx, __shfl_xor(mx, 2, 16));
                mx = fmaxf(mx, __shfl_xor(mx, 4, 16));
                mx = fmaxf(mx, __shfl_xor(mx, 8, 16));
                float sum = 0.f;
                #pragma unroll
                for (int ct = 0; ct < 3; ++ct) {
                    const float e = __expf(sh[hh][rt][ct][q] - mx);
                    sh[hh][rt][ct][q] = e;
                    sum += e;
                }
                sum += __shfl_xor(sum, 1, 16);
                sum += __shfl_xor(sum, 2, 16);
                sum += __shfl_xor(sum, 4, 16);
                sum += __shfl_xor(sum, 8, 16);
                inv_[hh][rt][q] = 1.0f / sum;
            }
        }
    }
    __syncthreads();   // Q/K slab reads done everywhere

    // ---- per head: stage P (into slK) + vT (into slQ), PV, store ----
    lds64_t vT = slQ;   // [32][64] region, Q dead
    #pragma unroll
    for (int hh = 0; hh < 2; ++hh) {
        const int h = wn * 2 + hh;
        // P
        #pragma unroll
        for (int rt = 0; rt < 3; ++rt) {
            #pragma unroll
            for (int q = 0; q < 4; ++q) {
                const int row = rt * 16 + lg * 4 + q;
                #pragma unroll
                for (int ct = 0; ct < 3; ++ct) {
                    const int m = ct * 16 + l15;
                    slK[row][(((m >> 3) ^ (row & 7)) * 8) + (m & 7)] = (__bf16)sh[hh][rt][ct][q];
                }
                const int mz = 48 + l15;
                slK[row][(((mz >> 3) ^ (row & 7)) * 8) + (mz & 7)] = (__bf16)0.0f;
            }
        }
        // vT (+bias), tokens 0..47; zero-pad tokens 48..63
        #pragma unroll
        for (int ct2 = 0; ct2 < 2; ++ct2) {
            const int ct = hh * 2 + ct2;
            const int d = ct2 * 16 + l15;
            const float vb = qkv_b[512 + wn * 64 + ct * 16 + l15];
            #pragma unroll
            for (int rt = 0; rt < 3; ++rt)
                #pragma unroll
                for (int q = 0; q < 4; ++q) {
                    const int m = rt * 16 + lg * 4 + q;
                    vT[d][(((m >> 3) ^ (d & 7)) * 8) + (m & 7)] = (__bf16)(acc3[2][rt][ct][q] + vb);
                }
        }
        for (int z = lane; z < 512; z += 64) {
            const int d = z >> 4, m = 48 + (z & 15);
            vT[d][(((m >> 3) ^ (d & 7)) * 8) + (m & 7)] = (__bf16)0.0f;
        }
        __syncthreads();

        // PV: out[48 x 32], K=64
        f32x4 ov[3][2];
        #pragma unroll
        for (int rt = 0; rt < 3; ++rt)
            #pragma unroll
            for (int cd = 0; cd < 2; ++cd) ov[rt][cd] = fzero;
        #pragma unroll
        for (int kk = 0; kk < 2; ++kk) {
            bf16x8 pa[3], bv[2];
            #pragma unroll
            for (int rt = 0; rt < 3; ++rt) {
                const int ar = rt * 16 + l15;
                pa[rt] = *(const bf16x8*)&slK[ar][((kk * 4 + lg) ^ (ar & 7)) * 8];
            }
            #pragma unroll
            for (int cd = 0; cd < 2; ++cd) {
                const int d = cd * 16 + l15;
                bv[cd] = *(const bf16x8*)&vT[d][((kk * 4 + lg) ^ (d & 7)) * 8];
            }
            #pragma unroll
            for (int rt = 0; rt < 3; ++rt)
                #pragma unroll
                for (int cd = 0; cd < 2; ++cd)
                    ov[rt][cd] = MFMA16(pa[rt], bv[cd], ov[rt][cd]);
        }
        #pragma unroll
        for (int rt = 0; rt < 3; ++rt)
            #pragma unroll
            for (int cd = 0; cd < 2; ++cd)
                #pragma unroll
                for (int q = 0; q < 4; ++q) {
                    const int n = rt * 16 + lg * 4 + q;
                    if (n < 36)
                        attnout[(rowbase + n) * 256 + h * 32 + cd * 16 + l15] =
                            (__bf16)(ov[rt][cd][q] * inv_[hh][rt][q]);
                }
        __syncthreads();   // slab reads done before next head restage
    }
}

// ---------------------------------------------------------------------------
// k2: MFMA proj (BM=128, 4x4 wave tiles) + roll permute + residual + LN1 -> x1
// grid 1152, block 512
// ---------------------------------------------------------------------------
__global__ __launch_bounds__(512) void k2_proj_ln(
    const __bf16* __restrict__ attnout, const __bf16* __restrict__ projT,
    const float* __restrict__ proj_b, const float* __restrict__ x,
    const float* __restrict__ n1w, const float* __restrict__ n1b,
    float* __restrict__ x1)
{
    __shared__ __attribute__((aligned(16))) __bf16 As[128][64];
    __shared__ __attribute__((aligned(16))) __bf16 Bs[256][64];
    __shared__ float ps[128][4], ps2[128][4];
    const int t = threadIdx.x;
    const int wid = t >> 6, lane = t & 63;
    const int l15 = lane & 15, lg = lane >> 4;
    const int mb = blockIdx.x;
    const int wm = wid >> 2, wn = wid & 3;

    const f32x4 fzero = {0.f, 0.f, 0.f, 0.f};
    f32x4 acc[4][4];
    #pragma unroll
    for (int i = 0; i < 4; ++i)
        #pragma unroll
        for (int j = 0; j < 4; ++j) acc[i][j] = fzero;

    for (int kc = 0; kc < 4; ++kc) {
        __syncthreads();
        for (int o = t; o < 128 * 8; o += 512) {
            const int row = o >> 3, kb = o & 7;
            *(uint4*)&As[row][SWB(row, kb) * 8] =
                *(const uint4*)(attnout + (size_t)(mb * 128 + row) * 256 + kc * 64 + kb * 8);
        }
        for (int o = t; o < 256 * 8; o += 512) {
            const int row = o >> 3, kb = o & 7;
            *(uint4*)&Bs[row][SWB(row, kb) * 8] =
                *(const uint4*)(projT + (size_t)row * 256 + kc * 64 + kb * 8);
        }
        __syncthreads();
        #pragma unroll
        for (int kk = 0; kk < 2; ++kk) {
            bf16x8 af[4], bfr[4];
            #pragma unroll
            for (int rt = 0; rt < 4; ++rt) {
                const int ar = wm * 64 + rt * 16 + l15;
                af[rt] = *(const bf16x8*)&As[ar][((kk * 4 + lg) ^ (ar & 7)) * 8];
            }
            #pragma unroll
            for (int ct = 0; ct < 4; ++ct) {
                const int br = wn * 64 + ct * 16 + l15;
                bfr[ct] = *(const bf16x8*)&Bs[br][((kk * 4 + lg) ^ (br & 7)) * 8];
            }
            #pragma unroll
            for (int rt = 0; rt < 4; ++rt)
                #pragma unroll
                for (int ct = 0; ct < 4; ++ct)
                    acc[rt][ct] = MFMA16(af[rt], bfr[ct], acc[rt][ct]);
        }
    }

    int dtok_[4][4];
    #pragma unroll
    for (int rt = 0; rt < 4; ++rt) {
        #pragma unroll
        for (int q = 0; q < 4; ++q) {
            const int rowl = wm * 64 + rt * 16 + lg * 4 + q;
            const int tok = mb * 128 + rowl;
            const int b = tok / LTOK, l = tok % LTOK;
            const int hh = l / 96, wwp = l % 96;
            const int dtok = b * LTOK + ((hh + 3) % 96) * 96 + ((wwp + 3) % 96);
            dtok_[rt][q] = dtok;
            float s = 0.f, s2 = 0.f;
            #pragma unroll
            for (int ct = 0; ct < 4; ++ct) {
                const int col = wn * 64 + ct * 16 + l15;
                const float v = acc[rt][ct][q] + proj_b[col] + ALPHA * x[(size_t)dtok * 256 + col];
                acc[rt][ct][q] = v;
                s += v; s2 += v * v;
            }
            s  += __shfl_xor(s, 1, 16);  s += __shfl_xor(s, 2, 16);
            s  += __shfl_xor(s, 4, 16);  s += __shfl_xor(s, 8, 16);
            s2 += __shfl_xor(s2, 1, 16); s2 += __shfl_xor(s2, 2, 16);
            s2 += __shfl_xor(s2, 4, 16); s2 += __shfl_xor(s2, 8, 16);
            if (l15 == 0) { ps[rowl][wn] = s; ps2[rowl][wn] = s2; }
        }
    }
    __syncthreads();
    #pragma unroll
    for (int rt = 0; rt < 4; ++rt) {
        #pragma unroll
        for (int q = 0; q < 4; ++q) {
            const int rowl = wm * 64 + rt * 16 + lg * 4 + q;
            const float S  = ps[rowl][0] + ps[rowl][1] + ps[rowl][2] + ps[rowl][3];
            const float S2 = ps2[rowl][0] + ps2[rowl][1] + ps2[rowl][2] + ps2[rowl][3];
            const float mu = S * (1.0f / 256.0f);
            const float var = S2 * (1.0f / 256.0f) - mu * mu;
            const float rstd = rsqrtf(var + 1e-5f);
            float* op = x1 + (size_t)dtok_[rt][q] * 256;
            #pragma unroll
            for (int ct = 0; ct < 4; ++ct) {
                const int col = wn * 64 + ct * 16 + l15;
                op[col] = (acc[rt][ct][q] - mu) * rstd * n1w[col] + n1b[col];
            }
        }
    }
}

// ---------------------------------------------------------------------------
// k3a: fc1 + GELU -> hmid bf16 (one token half). grid (576,4), block 512
// ---------------------------------------------------------------------------
__global__ __launch_bounds__(512) void k3a_fc1(
    const float* __restrict__ x1, const __bf16* __restrict__ w1T,
    const float* __restrict__ fc1_b, __bf16* __restrict__ hmid, int row0)
{
    __shared__ __attribute__((aligned(16))) __bf16 As[128][64];
    __shared__ __attribute__((aligned(16))) __bf16 Bs[256][64];
    const int t = threadIdx.x;
    const int wid = t >> 6, lane = t & 63;
    const int l15 = lane & 15, lg = lane >> 4;
    const int mb = blockIdx.x, nb = blockIdx.y;
    const int wm = wid >> 2, wn = wid & 3;

    const f32x4 fzero = {0.f, 0.f, 0.f, 0.f};
    f32x4 acc[4][4];
    #pragma unroll
    for (int i = 0; i < 4; ++i)
        #pragma unroll
        for (int j = 0; j < 4; ++j) acc[i][j] = fzero;

    for (int kc = 0; kc < 4; ++kc) {
        __syncthreads();
        for (int o = t; o < 128 * 8; o += 512) {
            const int row = o >> 3, kb = o & 7;
            const float* src = x1 + (size_t)(row0 + mb * 128 + row) * 256 + kc * 64 + kb * 8;
            const float4 f0 = *(const float4*)src;
            const float4 f1 = *(const float4*)(src + 4);
            bf16x8 p;
            p[0] = (__bf16)f0.x; p[1] = (__bf16)f0.y; p[2] = (__bf16)f0.z; p[3] = (__bf16)f0.w;
            p[4] = (__bf16)f1.x; p[5] = (__bf16)f1.y; p[6] = (__bf16)f1.z; p[7] = (__bf16)f1.w;
            *(bf16x8*)&As[row][SWB(row, kb) * 8] = p;
        }
        for (int o = t; o < 256 * 8; o += 512) {
            const int row = o >> 3, kb = o & 7;
            *(uint4*)&Bs[row][SWB(row, kb) * 8] =
                *(const uint4*)(w1T + (size_t)(nb * 256 + row) * 256 + kc * 64 + kb * 8);
        }
        __syncthreads();
        #pragma unroll
        for (int kk = 0; kk < 2; ++kk) {
            bf16x8 af[4], bfr[4];
            #pragma unroll
            for (int rt = 0; rt < 4; ++rt) {
                const int ar = wm * 64 + rt * 16 + l15;
                af[rt] = *(const bf16x8*)&As[ar][((kk * 4 + lg) ^ (ar & 7)) * 8];
            }
            #pragma unroll
            for (int ct = 0; ct < 4; ++ct) {
                const int br = wn * 64 + ct * 16 + l15;
                bfr[ct] = *(const bf16x8*)&Bs[br][((kk * 4 + lg) ^ (br & 7)) * 8];
            }
            #pragma unroll
            for (int rt = 0; rt < 4; ++rt)
                #pragma unroll
                for (int ct = 0; ct < 4; ++ct)
                    acc[rt][ct] = MFMA16(af[rt], bfr[ct], acc[rt][ct]);
        }
    }

    #pragma unroll
    for (int ct = 0; ct < 4; ++ct) {
        const int col = nb * 256 + wn * 64 + ct * 16 + l15;
        const float b1 = fc1_b[col];
        #pragma unroll
        for (int rt = 0; rt < 4; ++rt) {
            #pragma unroll
            for (int q = 0; q < 4; ++q) {
                const int rowl = mb * 128 + wm * 64 + rt * 16 + lg * 4 + q;
                hmid[(size_t)rowl * 1024 + col] = (__bf16)gelu_tanh(acc[rt][ct][q] + b1);
            }
        }
    }
}

// ---------------------------------------------------------------------------
// k3b: fc2 + residual + LN2 -> out (one token half). grid 576, block 512
// ---------------------------------------------------------------------------
__global__ __launch_bounds__(512) void k3b_fc2(
    const __bf16* __restrict__ hmid, const __bf16* __restrict__ w2T,
    const float* __restrict__ fc2_b, const float* __restrict__ x1,
    const float* __restrict__ n2w, const float* __restrict__ n2b,
    float* __restrict__ out, int row0)
{
    __shared__ __attribute__((aligned(16))) __bf16 As[128][64];
    __shared__ __attribute__((aligned(16))) __bf16 Bs[256][64];
    __shared__ float ps[128][4], ps2[128][4];
    const int t = threadIdx.x;
    const int wid = t >> 6, lane = t & 63;
    const int l15 = lane & 15, lg = lane >> 4;
    const int mb = blockIdx.x;
    const int wm = wid >> 2, wn = wid & 3;

    const f32x4 fzero = {0.f, 0.f, 0.f, 0.f};
    f32x4 acc[4][4];
    #pragma unroll
    for (int i = 0; i < 4; ++i)
        #pragma unroll
        for (int j = 0; j < 4; ++j) acc[i][j] = fzero;

    for (int kc = 0; kc < 16; ++kc) {
        __syncthreads();
        for (int o = t; o < 128 * 8; o += 512) {
            const int row = o >> 3, kb = o & 7;
            *(uint4*)&As[row][SWB(row, kb) * 8] =
                *(const uint4*)(hmid + (size_t)(mb * 128 + row) * 1024 + kc * 64 + kb * 8);
        }
        for (int o = t; o < 256 * 8; o += 512) {
            const int row = o >> 3, kb = o & 7;
            *(uint4*)&Bs[row][SWB(row, kb) * 8] =
                *(const uint4*)(w2T + (size_t)row * 1024 + kc * 64 + kb * 8);
        }
        __syncthreads();
        #pragma unroll
        for (int kk = 0; kk < 2; ++kk) {
            bf16x8 af[4], bfr[4];
            #pragma unroll
            for (int rt = 0; rt < 4; ++rt) {
                const int ar = wm * 64 + rt * 16 + l15;
                af[rt] = *(const bf16x8*)&As[ar][((kk * 4 + lg) ^ (ar & 7)) * 8];
            }
            #pragma unroll
            for (int ct = 0; ct < 4; ++ct) {
                const int br = wn * 64 + ct * 16 + l15;
                bfr[ct] = *(const bf16x8*)&Bs[br][((kk * 4 + lg) ^ (br & 7)) * 8];
            }
            #pragma unroll
            for (int rt = 0; rt < 4; ++rt)
                #pragma unroll
                for (int ct = 0; ct < 4; ++ct)
                    acc[rt][ct] = MFMA16(af[rt], bfr[ct], acc[rt][ct]);
        }
    }

    #pragma unroll
    for (int rt = 0; rt < 4; ++rt) {
        #pragma unroll
        for (int q = 0; q < 4; ++q) {
            const int rowl = wm * 64 + rt * 16 + lg * 4 + q;
            const size_t tok = (size_t)(row0 + mb * 128 + rowl);
            float s = 0.f, s2 = 0.f;
            #pragma unroll
            for (int ct = 0; ct < 4; ++ct) {
                const int col = wn * 64 + ct * 16 + l15;
                const float v = acc[rt][ct][q] + fc2_b[col] + ALPHA * x1[tok * 256 + col];
                acc[rt][ct][q] = v;
                s += v; s2 += v * v;
            }
            s  += __shfl_xor(s, 1, 16);  s += __shfl_xor(s, 2, 16);
            s  += __shfl_xor(s, 4, 16);  s += __shfl_xor(s, 8, 16);
            s2 += __shfl_xor(s2, 1, 16); s2 += __shfl_xor(s2, 2, 16);
            s2 += __shfl_xor(s2, 4, 16); s2 += __shfl_xor(s2, 8, 16);
            if (l15 == 0) { ps[rowl][wn] = s; ps2[rowl][wn] = s2; }
        }
    }
    __syncthreads();
    #pragma unroll
    for (int rt = 0; rt < 4; ++rt) {
        #pragma unroll
        for (int q = 0; q < 4; ++q) {
            const int rowl = wm * 64 + rt * 16 + lg * 4 + q;
            const size_t tok = (size_t)(row0 + mb * 128 + rowl);
            const float S  = ps[rowl][0] + ps[rowl][1] + ps[rowl][2] + ps[rowl][3];
            const float S2 = ps2[rowl][0] + ps2[rowl][1] + ps2[rowl][2] + ps2[rowl][3];
            const float mu = S * (1.0f / 256.0f);
            const float var = S2 * (1.0f / 256.0f) - mu * mu;
            const float rstd = rsqrtf(var + 1e-5f);
            float* op = out + tok * 256;
            #pragma unroll
            for (int ct = 0; ct < 4; ++ct) {
                const int col = wn * 64 + ct * 16 + l15;
                op[col] = (acc[rt][ct][q] - mu) * rstd * n2w[col] + n2b[col];
            }
        }
    }
}

// ---------------------------------------------------------------------------
extern "C" void kernel_launch(void* const* d_in, const int* in_sizes, int n_in,
                              void* d_out, int out_size, void* d_ws, size_t ws_size,
                              hipStream_t stream)
{
    const float* x          = (const float*)d_in[0];
    const float* qkv_w      = (const float*)d_in[1];
    const float* qkv_b      = (const float*)d_in[2];
    const float* bias_table = (const float*)d_in[3];
    const float* proj_w     = (const float*)d_in[4];
    const float* proj_b     = (const float*)d_in[5];
    const float* n1w        = (const float*)d_in[6];
    const float* n1b        = (const float*)d_in[7];
    const float* n2w        = (const float*)d_in[8];
    const float* n2b        = (const float*)d_in[9];
    const float* fc1_w      = (const float*)d_in[10];
    const float* fc1_b      = (const float*)d_in[11];
    const float* fc2_w      = (const float*)d_in[12];
    const float* fc2_b      = (const float*)d_in[13];
    float* out = (float*)d_out;

    // ws layout (bytes), total 303,562,752:
    //   [0,          150994944)  x1 fp32
    //   [150994944,  301989888)  hmid bf16, one half (overlays attnout after k2)
    //   [226492416,  301989888)  attnout bf16        (dead after k2)
    //   [301989888,  303562752)  weight tables
    char* ws = (char*)d_ws;
    float*  x1      = (float*)ws;
    __bf16* hmid    = (__bf16*)(ws + 150994944);
    __bf16* attnout = (__bf16*)(ws + 226492416);
    __bf16* qkvT    = (__bf16*)(ws + 301989888);
    __bf16* projT   = (__bf16*)(ws + 302383104);
    __bf16* w1T     = (__bf16*)(ws + 302514176);
    __bf16* w2T     = (__bf16*)(ws + 303038464);

    k0_prep<<<3072, 256, 0, stream>>>(qkv_w, proj_w, fc1_w, fc2_w, qkvT, projT, w1T, w2T);
    k1f_qkv_attn<<<2048, 512, 0, stream>>>(x, qkvT, qkv_b, bias_table, attnout);
    k2_proj_ln<<<1152, 512, 0, stream>>>(attnout, projT, proj_b, x, n1w, n1b, x1);
    for (int h = 0; h < 2; ++h) {
        k3a_fc1<<<dim3(576, 4), 512, 0, stream>>>(x1, w1T, fc1_b, hmid, h * 73728);
        k3b_fc2<<<576, 512, 0, stream>>>(hmid, w2T, fc2_b, x1, n2w, n2b, out, h * 73728);
    }
}

// Round 7
// 828.209 us; speedup vs baseline: 1.4016x; 1.2975x over previous
//
#include <hip/hip_runtime.h>
#include <math.h>

typedef __bf16 bf16x8 __attribute__((ext_vector_type(8)));
typedef float f32x4 __attribute__((ext_vector_type(4)));

#define NTOK 147456
#define LTOK 9216
#define ALPHA 1.8612097182041991f
#define QSCALE 5.656854249492380196f
#define MFMA16(a,b,c) __builtin_amdgcn_mfma_f32_16x16x32_bf16((a),(b),(c),0,0,0)
#define SWB(row,kb) ((kb) ^ ((row)&7))

__device__ __forceinline__ float gelu_tanh(float x) {
    const float u = 0.7978845608028654f * (x + 0.044715f * x * x * x);
    const float e = __expf(2.0f * u);
    const float th = 1.0f - 2.0f / (e + 1.0f);
    return 0.5f * x * (1.0f + th);
}

// async global->LDS, 16B per lane; LDS dest = wave-uniform base + lane*16
__device__ __forceinline__ void gll16(const void* g, void* l) {
    __builtin_amdgcn_global_load_lds(
        (const __attribute__((address_space(1))) void*)g,
        (__attribute__((address_space(3))) void*)l, 16, 0, 0);
}

// ---------------------------------------------------------------------------
// k0: weights -> bf16 transposed [out][k]
// ---------------------------------------------------------------------------
__global__ __launch_bounds__(256) void k0_prep(
    const float* __restrict__ qkv_w, const float* __restrict__ proj_w,
    const float* __restrict__ fc1_w, const float* __restrict__ fc2_w,
    __bf16* __restrict__ qkvT, __bf16* __restrict__ projT,
    __bf16* __restrict__ w1T, __bf16* __restrict__ w2T)
{
    const int id = blockIdx.x * 256 + threadIdx.x;
    if (id < 196608) {
        const int o = id >> 8, k = id & 255;
        qkvT[id] = (__bf16)qkv_w[k * 768 + o];
    } else if (id < 262144) {
        const int i = id - 196608, o = i >> 8, k = i & 255;
        projT[i] = (__bf16)proj_w[k * 256 + o];
    } else if (id < 524288) {
        const int i = id - 262144, o = i >> 8, k = i & 255;
        w1T[i] = (__bf16)fc1_w[k * 1024 + o];
    } else {
        const int i = id - 524288, o = i >> 10, k = i & 1023;
        w2T[i] = (__bf16)fc2_w[k * 256 + o];
    }
}

// ---------------------------------------------------------------------------
// k1f: fused QKV GEMM + attention. Block = 1 window (48 padded rows),
// wave = 1 head. grid 4096, block 512. LDS 80 KB -> 2 blocks/CU.
// GEMM: As[48][256] staged once; Bs[768][32] per K=32 chunk via gll.
// Attn: wave-private 10KB slab, ZERO barriers.
// ---------------------------------------------------------------------------
__global__ __launch_bounds__(512, 4) void k1f_qkv_attn(
    const float* __restrict__ x, const __bf16* __restrict__ qkvT,
    const float* __restrict__ qkv_b, const float* __restrict__ bias_table,
    __bf16* __restrict__ attnout)
{
    __shared__ __attribute__((aligned(16))) char SM[81920];
    typedef __bf16 (*a256_t)[256];
    typedef __bf16 (*b32_t)[32];
    typedef __bf16 (*s64_t)[64];
    a256_t As = (a256_t)SM;                   // [48][256] 24576 B
    b32_t  Bs = (b32_t)(SM + 24576);          // [768][32] 49152 B
    int* srcrow = (int*)(SM + 73728);         // 48 ints

    const int t = threadIdx.x;
    const int wid = t >> 6, lane = t & 63;
    const int l15 = lane & 15, lg = lane >> 4;
    const int blk = blockIdx.x;               // window 0..4095
    const int win = blk & 255;
    const int wh = win >> 4, ww = win & 15;
    const int h = wid;                        // head

    if (t < 48) {
        int n = t; if (n > 35) n = 35;
        const int b = blk >> 8;
        const int gh = (wh * 6 + n / 6 + 3) % 96;
        const int gw = (ww * 6 + n % 6 + 3) % 96;
        srcrow[t] = b * LTOK + gh * 96 + gw;
    }
    __syncthreads();

    // stage As [48][256] once (fp32 -> bf16, SWB swizzle on 16B chunks)
    for (int o = t; o < 48 * 32; o += 512) {
        const int row = o >> 5, kb = o & 31;
        const float* src = x + (size_t)srcrow[row] * 256 + kb * 8;
        const float4 f0 = *(const float4*)src;
        const float4 f1 = *(const float4*)(src + 4);
        bf16x8 p;
        p[0] = (__bf16)f0.x; p[1] = (__bf16)f0.y; p[2] = (__bf16)f0.z; p[3] = (__bf16)f0.w;
        p[4] = (__bf16)f1.x; p[5] = (__bf16)f1.y; p[6] = (__bf16)f1.z; p[7] = (__bf16)f1.w;
        *(bf16x8*)&As[row][SWB(row, kb) * 8] = p;
    }

    const f32x4 fzero = {0.f, 0.f, 0.f, 0.f};
    f32x4 acc[3][3][2];   // nb(Q,K,V) x rt x ct  = 72 VGPR
    #pragma unroll
    for (int nb = 0; nb < 3; ++nb)
        #pragma unroll
        for (int i = 0; i < 3; ++i)
            #pragma unroll
            for (int j = 0; j < 2; ++j) acc[nb][i][j] = fzero;

    for (int kc = 0; kc < 8; ++kc) {
        __syncthreads();   // prev Bs reads done (iter0: orders srcrow/As writes)
        // stage Bs[768][32] via gll: 6 x 1KB per wave, pre-swizzled source
        #pragma unroll
        for (int i = 0; i < 6; ++i) {
            const int r0 = wid * 96 + i * 16;
            const int row = r0 + (lane >> 2), kbl = lane & 3;
            gll16(qkvT + (size_t)row * 256 + kc * 32 + ((kbl ^ (row & 3)) * 8),
                  &Bs[r0][0]);
        }
        __syncthreads();
        bf16x8 af[3];
        #pragma unroll
        for (int rt = 0; rt < 3; ++rt) {
            const int ar = rt * 16 + l15;
            const int kb = kc * 4 + lg;
            af[rt] = *(const bf16x8*)&As[ar][SWB(ar, kb) * 8];
        }
        #pragma unroll
        for (int nb = 0; nb < 3; ++nb)
            #pragma unroll
            for (int ct = 0; ct < 2; ++ct) {
                const int br = nb * 256 + h * 32 + ct * 16 + l15;
                const bf16x8 bfr = *(const bf16x8*)&Bs[br][((lg ^ (br & 3))) * 8];
                #pragma unroll
                for (int rt = 0; rt < 3; ++rt)
                    acc[nb][rt][ct] = MFMA16(af[rt], bfr, acc[nb][rt][ct]);
            }
    }
    __syncthreads();   // all As/Bs reads done; slab region free. LAST barrier.

    // ---- wave-private attention (head h, window blk) ----
    s64_t slab = (s64_t)(SM + wid * 10240);          // [48][64]: Q|K, then P
    s64_t vT   = (s64_t)(SM + wid * 10240 + 6144);   // [32][64]
    const size_t rowbase = (size_t)blk * 36;

    int i2_[3], j2_[3], g2_[3];
    #pragma unroll
    for (int ct = 0; ct < 3; ++ct) {
        const int m = ct * 16 + l15;
        const int mm = m < 36 ? m : 35;
        i2_[ct] = mm / 6; j2_[ct] = mm - i2_[ct] * 6;
        const int hg = (wh < 15) ? 0 : (i2_[ct] < 3 ? 1 : 2);
        const int wg = (ww < 15) ? 0 : (j2_[ct] < 3 ? 1 : 2);
        g2_[ct] = hg * 3 + wg;
    }

    // stage Q (cols 0-31) and K (cols 32-63); half-preserving swizzle ^(tok&3)
    #pragma unroll
    for (int ct = 0; ct < 2; ++ct) {
        const int dq = ct * 16 + l15;
        const float qb  = qkv_b[h * 32 + dq];
        const float kb2 = qkv_b[256 + h * 32 + dq];
        #pragma unroll
        for (int rt = 0; rt < 3; ++rt)
            #pragma unroll
            for (int q = 0; q < 4; ++q) {
                const int tok = rt * 16 + lg * 4 + q;
                const int c = (((dq >> 3) ^ (tok & 3)) * 8) + (dq & 7);
                slab[tok][c]      = (__bf16)((acc[0][rt][ct][q] + qb) * QSCALE);
                slab[tok][32 + c] = (__bf16)(acc[1][rt][ct][q] + kb2);
            }
    }

    // S = Q K^T (K=32, one MFMA step)
    bf16x8 aq[3], bk[3];
    #pragma unroll
    for (int rt = 0; rt < 3; ++rt) {
        const int ar = rt * 16 + l15;
        aq[rt] = *(const bf16x8*)&slab[ar][((lg ^ (ar & 3))) * 8];
        bk[rt] = *(const bf16x8*)&slab[ar][32 + ((lg ^ (ar & 3))) * 8];
    }
    f32x4 s[3][3];
    #pragma unroll
    for (int rt = 0; rt < 3; ++rt)
        #pragma unroll
        for (int ct = 0; ct < 3; ++ct)
            s[rt][ct] = MFMA16(aq[rt], bk[ct], fzero);

    // bias + mask + softmax (deferred normalization)
    float inv_[3][4];
    #pragma unroll
    for (int rt = 0; rt < 3; ++rt) {
        #pragma unroll
        for (int q = 0; q < 4; ++q) {
            const int n0 = rt * 16 + lg * 4 + q;
            const int nn = n0 < 36 ? n0 : 35;
            const int i1 = nn / 6, j1 = nn - i1 * 6;
            const int hg1 = (wh < 15) ? 0 : (i1 < 3 ? 1 : 2);
            const int wg1 = (ww < 15) ? 0 : (j1 < 3 ? 1 : 2);
            const int g1 = hg1 * 3 + wg1;
            #pragma unroll
            for (int ct = 0; ct < 3; ++ct) {
                const int m = ct * 16 + l15;
                float val;
                if (m < 36) {
                    val = s[rt][ct][q] + bias_table[((i1 - i2_[ct] + 5) * 11 + (j1 - j2_[ct] + 5)) * 8 + h];
                    if (g1 != g2_[ct]) val -= 100.0f;
                } else {
                    val = -1e30f;
                }
                s[rt][ct][q] = val;
            }
            float mx = fmaxf(fmaxf(s[rt][0][q], s[rt][1][q]), s[rt][2][q]);
            mx = fmaxf(mx, __shfl_xor(mx, 1, 16));
            mx = fmaxf(mx, __shfl_xor(mx, 2, 16));
            mx = fmaxf(mx, __shfl_xor(mx, 4, 16));
            mx = fmaxf(mx, __shfl_xor(mx, 8, 16));
            float sum = 0.f;
            #pragma unroll
            for (int ct = 0; ct < 3; ++ct) {
                const float e = __expf(s[rt][ct][q] - mx);
                s[rt][ct][q] = e;
                sum += e;
            }
            sum += __shfl_xor(sum, 1, 16);
            sum += __shfl_xor(sum, 2, 16);
            sum += __shfl_xor(sum, 4, 16);
            sum += __shfl_xor(sum, 8, 16);
            inv_[rt][q] = 1.0f / sum;
        }
    }

    // P -> slab (overwrites Q/K; same-wave DS ordering), full SWB8 swizzle
    #pragma unroll
    for (int rt = 0; rt < 3; ++rt)
        #pragma unroll
        for (int q = 0; q < 4; ++q) {
            const int row = rt * 16 + lg * 4 + q;
            #pragma unroll
            for (int ct = 0; ct < 3; ++ct) {
                const int m = ct * 16 + l15;
                slab[row][(((m >> 3) ^ (row & 7)) * 8) + (m & 7)] = (__bf16)s[rt][ct][q];
            }
            const int mz = 48 + l15;
            slab[row][(((mz >> 3) ^ (row & 7)) * 8) + (mz & 7)] = (__bf16)0.0f;
        }

    // vT (+bias); zero-pad toks 48..63
    #pragma unroll
    for (int ct = 0; ct < 2; ++ct) {
        const int d = ct * 16 + l15;
        const float vb = qkv_b[512 + h * 32 + d];
        #pragma unroll
        for (int rt = 0; rt < 3; ++rt)
            #pragma unroll
            for (int q = 0; q < 4; ++q) {
                const int m = rt * 16 + lg * 4 + q;
                vT[d][(((m >> 3) ^ (d & 7)) * 8) + (m & 7)] = (__bf16)(acc[2][rt][ct][q] + vb);
            }
    }
    for (int z = lane; z < 512; z += 64) {
        const int d = z >> 4, m = 48 + (z & 15);
        vT[d][(((m >> 3) ^ (d & 7)) * 8) + (m & 7)] = (__bf16)0.0f;
    }

    // PV (K=64)
    f32x4 ov[3][2];
    #pragma unroll
    for (int rt = 0; rt < 3; ++rt)
        #pragma unroll
        for (int cd = 0; cd < 2; ++cd) ov[rt][cd] = fzero;
    #pragma unroll
    for (int kk = 0; kk < 2; ++kk) {
        bf16x8 pa[3], bv[2];
        #pragma unroll
        for (int rt = 0; rt < 3; ++rt) {
            const int ar = rt * 16 + l15;
            pa[rt] = *(const bf16x8*)&slab[ar][(((kk * 4 + lg) ^ (ar & 7))) * 8];
        }
        #pragma unroll
        for (int cd = 0; cd < 2; ++cd) {
            const int d = cd * 16 + l15;
            bv[cd] = *(const bf16x8*)&vT[d][(((kk * 4 + lg) ^ (d & 7))) * 8];
        }
        #pragma unroll
        for (int rt = 0; rt < 3; ++rt)
            #pragma unroll
            for (int cd = 0; cd < 2; ++cd)
                ov[rt][cd] = MFMA16(pa[rt], bv[cd], ov[rt][cd]);
    }

    #pragma unroll
    for (int rt = 0; rt < 3; ++rt)
        #pragma unroll
        for (int cd = 0; cd < 2; ++cd)
            #pragma unroll
            for (int q = 0; q < 4; ++q) {
                const int n = rt * 16 + lg * 4 + q;
                if (n < 36)
                    attnout[(rowbase + n) * 256 + h * 32 + cd * 16 + l15] =
                        (__bf16)(ov[rt][cd][q] * inv_[rt][q]);
            }
}

// ---------------------------------------------------------------------------
// k2: MFMA proj + roll permute + residual + LN1 -> x1b (bf16). grid 1152.
// ---------------------------------------------------------------------------
__global__ __launch_bounds__(512) void k2_proj_ln(
    const __bf16* __restrict__ attnout, const __bf16* __restrict__ projT,
    const float* __restrict__ proj_b, const float* __restrict__ x,
    const float* __restrict__ n1w, const float* __restrict__ n1b,
    __bf16* __restrict__ x1b)
{
    __shared__ __attribute__((aligned(16))) __bf16 As[128][64];
    __shared__ __attribute__((aligned(16))) __bf16 Bs[256][64];
    __shared__ float ps[128][4], ps2[128][4];
    const int t = threadIdx.x;
    const int wid = t >> 6, lane = t & 63;
    const int l15 = lane & 15, lg = lane >> 4;
    const int mb = blockIdx.x;
    const int wm = wid >> 2, wn = wid & 3;

    const f32x4 fzero = {0.f, 0.f, 0.f, 0.f};
    f32x4 acc[4][4];
    #pragma unroll
    for (int i = 0; i < 4; ++i)
        #pragma unroll
        for (int j = 0; j < 4; ++j) acc[i][j] = fzero;

    for (int kc = 0; kc < 4; ++kc) {
        __syncthreads();
        #pragma unroll
        for (int i = 0; i < 2; ++i) {
            const int r0 = wid * 16 + i * 8;
            const int row = r0 + (lane >> 3), kbl = lane & 7;
            gll16(attnout + (size_t)(mb * 128 + row) * 256 + kc * 64 + ((kbl ^ (row & 7)) * 8),
                  &As[r0][0]);
        }
        #pragma unroll
        for (int i = 0; i < 4; ++i) {
            const int r0 = wid * 32 + i * 8;
            const int row = r0 + (lane >> 3), kbl = lane & 7;
            gll16(projT + (size_t)row * 256 + kc * 64 + ((kbl ^ (row & 7)) * 8),
                  &Bs[r0][0]);
        }
        __syncthreads();
        #pragma unroll
        for (int kk = 0; kk < 2; ++kk) {
            bf16x8 af[4], bfr[4];
            #pragma unroll
            for (int rt = 0; rt < 4; ++rt) {
                const int ar = wm * 64 + rt * 16 + l15;
                af[rt] = *(const bf16x8*)&As[ar][((kk * 4 + lg) ^ (ar & 7)) * 8];
            }
            #pragma unroll
            for (int ct = 0; ct < 4; ++ct) {
                const int br = wn * 64 + ct * 16 + l15;
                bfr[ct] = *(const bf16x8*)&Bs[br][((kk * 4 + lg) ^ (br & 7)) * 8];
            }
            #pragma unroll
            for (int rt = 0; rt < 4; ++rt)
                #pragma unroll
                for (int ct = 0; ct < 4; ++ct)
                    acc[rt][ct] = MFMA16(af[rt], bfr[ct], acc[rt][ct]);
        }
    }

    int dtok_[4][4];
    #pragma unroll
    for (int rt = 0; rt < 4; ++rt) {
        #pragma unroll
        for (int q = 0; q < 4; ++q) {
            const int rowl = wm * 64 + rt * 16 + lg * 4 + q;
            const int tok = mb * 128 + rowl;
            const int b = tok / LTOK, l = tok % LTOK;
            const int hh = l / 96, wwp = l % 96;
            const int dtok = b * LTOK + ((hh + 3) % 96) * 96 + ((wwp + 3) % 96);
            dtok_[rt][q] = dtok;
            float s = 0.f, s2 = 0.f;
            #pragma unroll
            for (int ct = 0; ct < 4; ++ct) {
                const int col = wn * 64 + ct * 16 + l15;
                const float v = acc[rt][ct][q] + proj_b[col] + ALPHA * x[(size_t)dtok * 256 + col];
                acc[rt][ct][q] = v;
                s += v; s2 += v * v;
            }
            s  += __shfl_xor(s, 1, 16);  s += __shfl_xor(s, 2, 16);
            s  += __shfl_xor(s, 4, 16);  s += __shfl_xor(s, 8, 16);
            s2 += __shfl_xor(s2, 1, 16); s2 += __shfl_xor(s2, 2, 16);
            s2 += __shfl_xor(s2, 4, 16); s2 += __shfl_xor(s2, 8, 16);
            if (l15 == 0) { ps[rowl][wn] = s; ps2[rowl][wn] = s2; }
        }
    }
    __syncthreads();
    #pragma unroll
    for (int rt = 0; rt < 4; ++rt) {
        #pragma unroll
        for (int q = 0; q < 4; ++q) {
            const int rowl = wm * 64 + rt * 16 + lg * 4 + q;
            const float S  = ps[rowl][0] + ps[rowl][1] + ps[rowl][2] + ps[rowl][3];
            const float S2 = ps2[rowl][0] + ps2[rowl][1] + ps2[rowl][2] + ps2[rowl][3];
            const float mu = S * (1.0f / 256.0f);
            const float var = S2 * (1.0f / 256.0f) - mu * mu;
            const float rstd = rsqrtf(var + 1e-5f);
            __bf16* op = x1b + (size_t)dtok_[rt][q] * 256;
            #pragma unroll
            for (int ct = 0; ct < 4; ++ct) {
                const int col = wn * 64 + ct * 16 + l15;
                op[col] = (__bf16)((acc[rt][ct][q] - mu) * rstd * n1w[col] + n1b[col]);
            }
        }
    }
}

// ---------------------------------------------------------------------------
// k3a: fc1 + GELU -> hmid bf16 (one token half). grid (576,4), block 512
// ---------------------------------------------------------------------------
__global__ __launch_bounds__(512) void k3a_fc1(
    const __bf16* __restrict__ x1b, const __bf16* __restrict__ w1T,
    const float* __restrict__ fc1_b, __bf16* __restrict__ hmid, int row0)
{
    __shared__ __attribute__((aligned(16))) __bf16 As[128][64];
    __shared__ __attribute__((aligned(16))) __bf16 Bs[256][64];
    const int t = threadIdx.x;
    const int wid = t >> 6, lane = t & 63;
    const int l15 = lane & 15, lg = lane >> 4;
    const int mb = blockIdx.x, nb = blockIdx.y;
    const int wm = wid >> 2, wn = wid & 3;

    const f32x4 fzero = {0.f, 0.f, 0.f, 0.f};
    f32x4 acc[4][4];
    #pragma unroll
    for (int i = 0; i < 4; ++i)
        #pragma unroll
        for (int j = 0; j < 4; ++j) acc[i][j] = fzero;

    for (int kc = 0; kc < 4; ++kc) {
        __syncthreads();
        #pragma unroll
        for (int i = 0; i < 2; ++i) {
            const int r0 = wid * 16 + i * 8;
            const int row = r0 + (lane >> 3), kbl = lane & 7;
            gll16(x1b + (size_t)(row0 + mb * 128 + row) * 256 + kc * 64 + ((kbl ^ (row & 7)) * 8),
                  &As[r0][0]);
        }
        #pragma unroll
        for (int i = 0; i < 4; ++i) {
            const int r0 = wid * 32 + i * 8;
            const int row = r0 + (lane >> 3), kbl = lane & 7;
            gll16(w1T + (size_t)(nb * 256 + row) * 256 + kc * 64 + ((kbl ^ (row & 7)) * 8),
                  &Bs[r0][0]);
        }
        __syncthreads();
        #pragma unroll
        for (int kk = 0; kk < 2; ++kk) {
            bf16x8 af[4], bfr[4];
            #pragma unroll
            for (int rt = 0; rt < 4; ++rt) {
                const int ar = wm * 64 + rt * 16 + l15;
                af[rt] = *(const bf16x8*)&As[ar][((kk * 4 + lg) ^ (ar & 7)) * 8];
            }
            #pragma unroll
            for (int ct = 0; ct < 4; ++ct) {
                const int br = wn * 64 + ct * 16 + l15;
                bfr[ct] = *(const bf16x8*)&Bs[br][((kk * 4 + lg) ^ (br & 7)) * 8];
            }
            #pragma unroll
            for (int rt = 0; rt < 4; ++rt)
                #pragma unroll
                for (int ct = 0; ct < 4; ++ct)
                    acc[rt][ct] = MFMA16(af[rt], bfr[ct], acc[rt][ct]);
        }
    }

    #pragma unroll
    for (int ct = 0; ct < 4; ++ct) {
        const int col = nb * 256 + wn * 64 + ct * 16 + l15;
        const float b1 = fc1_b[col];
        #pragma unroll
        for (int rt = 0; rt < 4; ++rt) {
            #pragma unroll
            for (int q = 0; q < 4; ++q) {
                const int rowl = mb * 128 + wm * 64 + rt * 16 + lg * 4 + q;
                hmid[(size_t)rowl * 1024 + col] = (__bf16)gelu_tanh(acc[rt][ct][q] + b1);
            }
        }
    }
}

// ---------------------------------------------------------------------------
// k3b: fc2 + residual + LN2 -> out (one token half). grid 576, block 512
// ---------------------------------------------------------------------------
__global__ __launch_bounds__(512) void k3b_fc2(
    const __bf16* __restrict__ hmid, const __bf16* __restrict__ w2T,
    const float* __restrict__ fc2_b, const __bf16* __restrict__ x1b,
    const float* __restrict__ n2w, const float* __restrict__ n2b,
    float* __restrict__ out, int row0)
{
    __shared__ __attribute__((aligned(16))) __bf16 As[128][64];
    __shared__ __attribute__((aligned(16))) __bf16 Bs[256][64];
    __shared__ float ps[128][4], ps2[128][4];
    const int t = threadIdx.x;
    const int wid = t >> 6, lane = t & 63;
    const int l15 = lane & 15, lg = lane >> 4;
    const int mb = blockIdx.x;
    const int wm = wid >> 2, wn = wid & 3;

    const f32x4 fzero = {0.f, 0.f, 0.f, 0.f};
    f32x4 acc[4][4];
    #pragma unroll
    for (int i = 0; i < 4; ++i)
        #pragma unroll
        for (int j = 0; j < 4; ++j) acc[i][j] = fzero;

    for (int kc = 0; kc < 16; ++kc) {
        __syncthreads();
        #pragma unroll
        for (int i = 0; i < 2; ++i) {
            const int r0 = wid * 16 + i * 8;
            const int row = r0 + (lane >> 3), kbl = lane & 7;
            gll16(hmid + (size_t)(mb * 128 + row) * 1024 + kc * 64 + ((kbl ^ (row & 7)) * 8),
                  &As[r0][0]);
        }
        #pragma unroll
        for (int i = 0; i < 4; ++i) {
            const int r0 = wid * 32 + i * 8;
            const int row = r0 + (lane >> 3), kbl = lane & 7;
            gll16(w2T + (size_t)row * 1024 + kc * 64 + ((kbl ^ (row & 7)) * 8),
                  &Bs[r0][0]);
        }
        __syncthreads();
        #pragma unroll
        for (int kk = 0; kk < 2; ++kk) {
            bf16x8 af[4], bfr[4];
            #pragma unroll
            for (int rt = 0; rt < 4; ++rt) {
                const int ar = wm * 64 + rt * 16 + l15;
                af[rt] = *(const bf16x8*)&As[ar][((kk * 4 + lg) ^ (ar & 7)) * 8];
            }
            #pragma unroll
            for (int ct = 0; ct < 4; ++ct) {
                const int br = wn * 64 + ct * 16 + l15;
                bfr[ct] = *(const bf16x8*)&Bs[br][((kk * 4 + lg) ^ (br & 7)) * 8];
            }
            #pragma unroll
            for (int rt = 0; rt < 4; ++rt)
                #pragma unroll
                for (int ct = 0; ct < 4; ++ct)
                    acc[rt][ct] = MFMA16(af[rt], bfr[ct], acc[rt][ct]);
        }
    }

    #pragma unroll
    for (int rt = 0; rt < 4; ++rt) {
        #pragma unroll
        for (int q = 0; q < 4; ++q) {
            const int rowl = wm * 64 + rt * 16 + lg * 4 + q;
            const size_t tok = (size_t)(row0 + mb * 128 + rowl);
            float s = 0.f, s2 = 0.f;
            #pragma unroll
            for (int ct = 0; ct < 4; ++ct) {
                const int col = wn * 64 + ct * 16 + l15;
                const float v = acc[rt][ct][q] + fc2_b[col] + ALPHA * (float)x1b[tok * 256 + col];
                acc[rt][ct][q] = v;
                s += v; s2 += v * v;
            }
            s  += __shfl_xor(s, 1, 16);  s += __shfl_xor(s, 2, 16);
            s  += __shfl_xor(s, 4, 16);  s += __shfl_xor(s, 8, 16);
            s2 += __shfl_xor(s2, 1, 16); s2 += __shfl_xor(s2, 2, 16);
            s2 += __shfl_xor(s2, 4, 16); s2 += __shfl_xor(s2, 8, 16);
            if (l15 == 0) { ps[rowl][wn] = s; ps2[rowl][wn] = s2; }
        }
    }
    __syncthreads();
    #pragma unroll
    for (int rt = 0; rt < 4; ++rt) {
        #pragma unroll
        for (int q = 0; q < 4; ++q) {
            const int rowl = wm * 64 + rt * 16 + lg * 4 + q;
            const size_t tok = (size_t)(row0 + mb * 128 + rowl);
            const float S  = ps[rowl][0] + ps[rowl][1] + ps[rowl][2] + ps[rowl][3];
            const float S2 = ps2[rowl][0] + ps2[rowl][1] + ps2[rowl][2] + ps2[rowl][3];
            const float mu = S * (1.0f / 256.0f);
            const float var = S2 * (1.0f / 256.0f) - mu * mu;
            const float rstd = rsqrtf(var + 1e-5f);
            float* op = out + tok * 256;
            #pragma unroll
            for (int ct = 0; ct < 4; ++ct) {
                const int col = wn * 64 + ct * 16 + l15;
                op[col] = (acc[rt][ct][q] - mu) * rstd * n2w[col] + n2b[col];
            }
        }
    }
}

// ---------------------------------------------------------------------------
extern "C" void kernel_launch(void* const* d_in, const int* in_sizes, int n_in,
                              void* d_out, int out_size, void* d_ws, size_t ws_size,
                              hipStream_t stream)
{
    const float* x          = (const float*)d_in[0];
    const float* qkv_w      = (const float*)d_in[1];
    const float* qkv_b      = (const float*)d_in[2];
    const float* bias_table = (const float*)d_in[3];
    const float* proj_w     = (const float*)d_in[4];
    const float* proj_b     = (const float*)d_in[5];
    const float* n1w        = (const float*)d_in[6];
    const float* n1b        = (const float*)d_in[7];
    const float* n2w        = (const float*)d_in[8];
    const float* n2b        = (const float*)d_in[9];
    const float* fc1_w      = (const float*)d_in[10];
    const float* fc1_b      = (const float*)d_in[11];
    const float* fc2_w      = (const float*)d_in[12];
    const float* fc2_b      = (const float*)d_in[13];
    float* out = (float*)d_out;

    // ws layout (bytes), total 303,562,752:
    //   [0,           75497472)  x1b bf16
    //   [150994944,  301989888)  hmid bf16, one half
    //   [226492416,  301989888)  attnout bf16 (dead after k2; hmid overlays)
    //   [301989888,  303562752)  weight tables
    char* ws = (char*)d_ws;
    __bf16* x1b     = (__bf16*)ws;
    __bf16* hmid    = (__bf16*)(ws + 150994944);
    __bf16* attnout = (__bf16*)(ws + 226492416);
    __bf16* qkvT    = (__bf16*)(ws + 301989888);
    __bf16* projT   = (__bf16*)(ws + 302383104);
    __bf16* w1T     = (__bf16*)(ws + 302514176);
    __bf16* w2T     = (__bf16*)(ws + 303038464);

    k0_prep<<<3072, 256, 0, stream>>>(qkv_w, proj_w, fc1_w, fc2_w, qkvT, projT, w1T, w2T);
    k1f_qkv_attn<<<4096, 512, 0, stream>>>(x, qkvT, qkv_b, bias_table, attnout);
    k2_proj_ln<<<1152, 512, 0, stream>>>(attnout, projT, proj_b, x, n1w, n1b, x1b);
    for (int h = 0; h < 2; ++h) {
        k3a_fc1<<<dim3(576, 4), 512, 0, stream>>>(x1b, w1T, fc1_b, hmid, h * 73728);
        k3b_fc2<<<576, 512, 0, stream>>>(hmid, w2T, fc2_b, x1b, n2w, n2b, out, h * 73728);
    }
}

// Round 8
// 682.959 us; speedup vs baseline: 1.6997x; 1.2127x over previous
//
#include <hip/hip_runtime.h>
#include <math.h>

typedef __bf16 bf16x8 __attribute__((ext_vector_type(8)));
typedef float f32x4 __attribute__((ext_vector_type(4)));

#define NTOK 147456
#define LTOK 9216
#define ALPHA 1.8612097182041991f
#define QSCALE 5.656854249492380196f
#define MFMA16(a,b,c) __builtin_amdgcn_mfma_f32_16x16x32_bf16((a),(b),(c),0,0,0)
#define SWB(row,kb) ((kb) ^ ((row)&7))

__device__ __forceinline__ float gelu_tanh(float x) {
    const float u = 0.7978845608028654f * (x + 0.044715f * x * x * x);
    const float e = __expf(2.0f * u);
    const float th = 1.0f - 2.0f / (e + 1.0f);
    return 0.5f * x * (1.0f + th);
}

// async global->LDS, 16B per lane; LDS dest = wave-uniform base + lane*16
__device__ __forceinline__ void gll16(const void* g, void* l) {
    __builtin_amdgcn_global_load_lds(
        (const __attribute__((address_space(1))) void*)g,
        (__attribute__((address_space(3))) void*)l, 16, 0, 0);
}

// ---------------------------------------------------------------------------
// k0: weights -> bf16 transposed [out][k]
// ---------------------------------------------------------------------------
__global__ __launch_bounds__(256) void k0_prep(
    const float* __restrict__ qkv_w, const float* __restrict__ proj_w,
    const float* __restrict__ fc1_w, const float* __restrict__ fc2_w,
    __bf16* __restrict__ qkvT, __bf16* __restrict__ projT,
    __bf16* __restrict__ w1T, __bf16* __restrict__ w2T)
{
    const int id = blockIdx.x * 256 + threadIdx.x;
    if (id < 196608) {
        const int o = id >> 8, k = id & 255;
        qkvT[id] = (__bf16)qkv_w[k * 768 + o];
    } else if (id < 262144) {
        const int i = id - 196608, o = i >> 8, k = i & 255;
        projT[i] = (__bf16)proj_w[k * 256 + o];
    } else if (id < 524288) {
        const int i = id - 262144, o = i >> 8, k = i & 255;
        w1T[i] = (__bf16)fc1_w[k * 1024 + o];
    } else {
        const int i = id - 524288, o = i >> 10, k = i & 1023;
        w2T[i] = (__bf16)fc2_w[k * 256 + o];
    }
}

// ---------------------------------------------------------------------------
// k1f: fused QKV GEMM + attention. Block = 1 window (48 padded rows),
// wave = 1 head. grid 4096, block 512. LDS 80 KB -> 2 blocks/CU.
// ---------------------------------------------------------------------------
__global__ __launch_bounds__(512, 4) void k1f_qkv_attn(
    const float* __restrict__ x, const __bf16* __restrict__ qkvT,
    const float* __restrict__ qkv_b, const float* __restrict__ bias_table,
    __bf16* __restrict__ attnout)
{
    __shared__ __attribute__((aligned(16))) char SM[81920];
    typedef __bf16 (*a256_t)[256];
    typedef __bf16 (*b32_t)[32];
    typedef __bf16 (*s64_t)[64];
    a256_t As = (a256_t)SM;                   // [48][256] 24576 B
    b32_t  Bs = (b32_t)(SM + 24576);          // [768][32] 49152 B
    int* srcrow = (int*)(SM + 73728);         // 48 ints

    const int t = threadIdx.x;
    const int wid = t >> 6, lane = t & 63;
    const int l15 = lane & 15, lg = lane >> 4;
    const int blk = blockIdx.x;               // window 0..4095
    const int win = blk & 255;
    const int wh = win >> 4, ww = win & 15;
    const int h = wid;                        // head

    if (t < 48) {
        int n = t; if (n > 35) n = 35;
        const int b = blk >> 8;
        const int gh = (wh * 6 + n / 6 + 3) % 96;
        const int gw = (ww * 6 + n % 6 + 3) % 96;
        srcrow[t] = b * LTOK + gh * 96 + gw;
    }
    __syncthreads();

    for (int o = t; o < 48 * 32; o += 512) {
        const int row = o >> 5, kb = o & 31;
        const float* src = x + (size_t)srcrow[row] * 256 + kb * 8;
        const float4 f0 = *(const float4*)src;
        const float4 f1 = *(const float4*)(src + 4);
        bf16x8 p;
        p[0] = (__bf16)f0.x; p[1] = (__bf16)f0.y; p[2] = (__bf16)f0.z; p[3] = (__bf16)f0.w;
        p[4] = (__bf16)f1.x; p[5] = (__bf16)f1.y; p[6] = (__bf16)f1.z; p[7] = (__bf16)f1.w;
        *(bf16x8*)&As[row][SWB(row, kb) * 8] = p;
    }

    const f32x4 fzero = {0.f, 0.f, 0.f, 0.f};
    f32x4 acc[3][3][2];
    #pragma unroll
    for (int nb = 0; nb < 3; ++nb)
        #pragma unroll
        for (int i = 0; i < 3; ++i)
            #pragma unroll
            for (int j = 0; j < 2; ++j) acc[nb][i][j] = fzero;

    for (int kc = 0; kc < 8; ++kc) {
        __syncthreads();
        #pragma unroll
        for (int i = 0; i < 6; ++i) {
            const int r0 = wid * 96 + i * 16;
            const int row = r0 + (lane >> 2), kbl = lane & 3;
            gll16(qkvT + (size_t)row * 256 + kc * 32 + ((kbl ^ (row & 3)) * 8),
                  &Bs[r0][0]);
        }
        __syncthreads();
        bf16x8 af[3];
        #pragma unroll
        for (int rt = 0; rt < 3; ++rt) {
            const int ar = rt * 16 + l15;
            const int kb = kc * 4 + lg;
            af[rt] = *(const bf16x8*)&As[ar][SWB(ar, kb) * 8];
        }
        #pragma unroll
        for (int nb = 0; nb < 3; ++nb)
            #pragma unroll
            for (int ct = 0; ct < 2; ++ct) {
                const int br = nb * 256 + h * 32 + ct * 16 + l15;
                const bf16x8 bfr = *(const bf16x8*)&Bs[br][((lg ^ (br & 3))) * 8];
                #pragma unroll
                for (int rt = 0; rt < 3; ++rt)
                    acc[nb][rt][ct] = MFMA16(af[rt], bfr, acc[nb][rt][ct]);
            }
    }
    __syncthreads();

    s64_t slab = (s64_t)(SM + wid * 10240);
    s64_t vT   = (s64_t)(SM + wid * 10240 + 6144);
    const size_t rowbase = (size_t)blk * 36;

    int i2_[3], j2_[3], g2_[3];
    #pragma unroll
    for (int ct = 0; ct < 3; ++ct) {
        const int m = ct * 16 + l15;
        const int mm = m < 36 ? m : 35;
        i2_[ct] = mm / 6; j2_[ct] = mm - i2_[ct] * 6;
        const int hg = (wh < 15) ? 0 : (i2_[ct] < 3 ? 1 : 2);
        const int wg = (ww < 15) ? 0 : (j2_[ct] < 3 ? 1 : 2);
        g2_[ct] = hg * 3 + wg;
    }

    #pragma unroll
    for (int ct = 0; ct < 2; ++ct) {
        const int dq = ct * 16 + l15;
        const float qb  = qkv_b[h * 32 + dq];
        const float kb2 = qkv_b[256 + h * 32 + dq];
        #pragma unroll
        for (int rt = 0; rt < 3; ++rt)
            #pragma unroll
            for (int q = 0; q < 4; ++q) {
                const int tok = rt * 16 + lg * 4 + q;
                const int c = (((dq >> 3) ^ (tok & 3)) * 8) + (dq & 7);
                slab[tok][c]      = (__bf16)((acc[0][rt][ct][q] + qb) * QSCALE);
                slab[tok][32 + c] = (__bf16)(acc[1][rt][ct][q] + kb2);
            }
    }

    bf16x8 aq[3], bk[3];
    #pragma unroll
    for (int rt = 0; rt < 3; ++rt) {
        const int ar = rt * 16 + l15;
        aq[rt] = *(const bf16x8*)&slab[ar][((lg ^ (ar & 3))) * 8];
        bk[rt] = *(const bf16x8*)&slab[ar][32 + ((lg ^ (ar & 3))) * 8];
    }
    f32x4 s[3][3];
    #pragma unroll
    for (int rt = 0; rt < 3; ++rt)
        #pragma unroll
        for (int ct = 0; ct < 3; ++ct)
            s[rt][ct] = MFMA16(aq[rt], bk[ct], fzero);

    float inv_[3][4];
    #pragma unroll
    for (int rt = 0; rt < 3; ++rt) {
        #pragma unroll
        for (int q = 0; q < 4; ++q) {
            const int n0 = rt * 16 + lg * 4 + q;
            const int nn = n0 < 36 ? n0 : 35;
            const int i1 = nn / 6, j1 = nn - i1 * 6;
            const int hg1 = (wh < 15) ? 0 : (i1 < 3 ? 1 : 2);
            const int wg1 = (ww < 15) ? 0 : (j1 < 3 ? 1 : 2);
            const int g1 = hg1 * 3 + wg1;
            #pragma unroll
            for (int ct = 0; ct < 3; ++ct) {
                const int m = ct * 16 + l15;
                float val;
                if (m < 36) {
                    val = s[rt][ct][q] + bias_table[((i1 - i2_[ct] + 5) * 11 + (j1 - j2_[ct] + 5)) * 8 + h];
                    if (g1 != g2_[ct]) val -= 100.0f;
                } else {
                    val = -1e30f;
                }
                s[rt][ct][q] = val;
            }
            float mx = fmaxf(fmaxf(s[rt][0][q], s[rt][1][q]), s[rt][2][q]);
            mx = fmaxf(mx, __shfl_xor(mx, 1, 16));
            mx = fmaxf(mx, __shfl_xor(mx, 2, 16));
            mx = fmaxf(mx, __shfl_xor(mx, 4, 16));
            mx = fmaxf(mx, __shfl_xor(mx, 8, 16));
            float sum = 0.f;
            #pragma unroll
            for (int ct = 0; ct < 3; ++ct) {
                const float e = __expf(s[rt][ct][q] - mx);
                s[rt][ct][q] = e;
                sum += e;
            }
            sum += __shfl_xor(sum, 1, 16);
            sum += __shfl_xor(sum, 2, 16);
            sum += __shfl_xor(sum, 4, 16);
            sum += __shfl_xor(sum, 8, 16);
            inv_[rt][q] = 1.0f / sum;
        }
    }

    #pragma unroll
    for (int rt = 0; rt < 3; ++rt)
        #pragma unroll
        for (int q = 0; q < 4; ++q) {
            const int row = rt * 16 + lg * 4 + q;
            #pragma unroll
            for (int ct = 0; ct < 3; ++ct) {
                const int m = ct * 16 + l15;
                slab[row][(((m >> 3) ^ (row & 7)) * 8) + (m & 7)] = (__bf16)s[rt][ct][q];
            }
            const int mz = 48 + l15;
            slab[row][(((mz >> 3) ^ (row & 7)) * 8) + (mz & 7)] = (__bf16)0.0f;
        }

    #pragma unroll
    for (int ct = 0; ct < 2; ++ct) {
        const int d = ct * 16 + l15;
        const float vb = qkv_b[512 + h * 32 + d];
        #pragma unroll
        for (int rt = 0; rt < 3; ++rt)
            #pragma unroll
            for (int q = 0; q < 4; ++q) {
                const int m = rt * 16 + lg * 4 + q;
                vT[d][(((m >> 3) ^ (d & 7)) * 8) + (m & 7)] = (__bf16)(acc[2][rt][ct][q] + vb);
            }
    }
    for (int z = lane; z < 512; z += 64) {
        const int d = z >> 4, m = 48 + (z & 15);
        vT[d][(((m >> 3) ^ (d & 7)) * 8) + (m & 7)] = (__bf16)0.0f;
    }

    f32x4 ov[3][2];
    #pragma unroll
    for (int rt = 0; rt < 3; ++rt)
        #pragma unroll
        for (int cd = 0; cd < 2; ++cd) ov[rt][cd] = fzero;
    #pragma unroll
    for (int kk = 0; kk < 2; ++kk) {
        bf16x8 pa[3], bv[2];
        #pragma unroll
        for (int rt = 0; rt < 3; ++rt) {
            const int ar = rt * 16 + l15;
            pa[rt] = *(const bf16x8*)&slab[ar][(((kk * 4 + lg) ^ (ar & 7))) * 8];
        }
        #pragma unroll
        for (int cd = 0; cd < 2; ++cd) {
            const int d = cd * 16 + l15;
            bv[cd] = *(const bf16x8*)&vT[d][(((kk * 4 + lg) ^ (d & 7))) * 8];
        }
        #pragma unroll
        for (int rt = 0; rt < 3; ++rt)
            #pragma unroll
            for (int cd = 0; cd < 2; ++cd)
                ov[rt][cd] = MFMA16(pa[rt], bv[cd], ov[rt][cd]);
    }

    #pragma unroll
    for (int rt = 0; rt < 3; ++rt)
        #pragma unroll
        for (int cd = 0; cd < 2; ++cd)
            #pragma unroll
            for (int q = 0; q < 4; ++q) {
                const int n = rt * 16 + lg * 4 + q;
                if (n < 36)
                    attnout[(rowbase + n) * 256 + h * 32 + cd * 16 + l15] =
                        (__bf16)(ov[rt][cd][q] * inv_[rt][q]);
            }
}

// ---------------------------------------------------------------------------
// k2: MFMA proj + roll permute + residual + LN1 -> x1b (bf16). grid 1152.
// ---------------------------------------------------------------------------
__global__ __launch_bounds__(512) void k2_proj_ln(
    const __bf16* __restrict__ attnout, const __bf16* __restrict__ projT,
    const float* __restrict__ proj_b, const float* __restrict__ x,
    const float* __restrict__ n1w, const float* __restrict__ n1b,
    __bf16* __restrict__ x1b)
{
    __shared__ __attribute__((aligned(16))) __bf16 As[128][64];
    __shared__ __attribute__((aligned(16))) __bf16 Bs[256][64];
    __shared__ float ps[128][4], ps2[128][4];
    const int t = threadIdx.x;
    const int wid = t >> 6, lane = t & 63;
    const int l15 = lane & 15, lg = lane >> 4;
    const int mb = blockIdx.x;
    const int wm = wid >> 2, wn = wid & 3;

    const f32x4 fzero = {0.f, 0.f, 0.f, 0.f};
    f32x4 acc[4][4];
    #pragma unroll
    for (int i = 0; i < 4; ++i)
        #pragma unroll
        for (int j = 0; j < 4; ++j) acc[i][j] = fzero;

    for (int kc = 0; kc < 4; ++kc) {
        __syncthreads();
        #pragma unroll
        for (int i = 0; i < 2; ++i) {
            const int r0 = wid * 16 + i * 8;
            const int row = r0 + (lane >> 3), kbl = lane & 7;
            gll16(attnout + (size_t)(mb * 128 + row) * 256 + kc * 64 + ((kbl ^ (row & 7)) * 8),
                  &As[r0][0]);
        }
        #pragma unroll
        for (int i = 0; i < 4; ++i) {
            const int r0 = wid * 32 + i * 8;
            const int row = r0 + (lane >> 3), kbl = lane & 7;
            gll16(projT + (size_t)row * 256 + kc * 64 + ((kbl ^ (row & 7)) * 8),
                  &Bs[r0][0]);
        }
        __syncthreads();
        #pragma unroll
        for (int kk = 0; kk < 2; ++kk) {
            bf16x8 af[4], bfr[4];
            #pragma unroll
            for (int rt = 0; rt < 4; ++rt) {
                const int ar = wm * 64 + rt * 16 + l15;
                af[rt] = *(const bf16x8*)&As[ar][((kk * 4 + lg) ^ (ar & 7)) * 8];
            }
            #pragma unroll
            for (int ct = 0; ct < 4; ++ct) {
                const int br = wn * 64 + ct * 16 + l15;
                bfr[ct] = *(const bf16x8*)&Bs[br][((kk * 4 + lg) ^ (br & 7)) * 8];
            }
            #pragma unroll
            for (int rt = 0; rt < 4; ++rt)
                #pragma unroll
                for (int ct = 0; ct < 4; ++ct)
                    acc[rt][ct] = MFMA16(af[rt], bfr[ct], acc[rt][ct]);
        }
    }

    int dtok_[4][4];
    #pragma unroll
    for (int rt = 0; rt < 4; ++rt) {
        #pragma unroll
        for (int q = 0; q < 4; ++q) {
            const int rowl = wm * 64 + rt * 16 + lg * 4 + q;
            const int tok = mb * 128 + rowl;
            const int b = tok / LTOK, l = tok % LTOK;
            const int hh = l / 96, wwp = l % 96;
            const int dtok = b * LTOK + ((hh + 3) % 96) * 96 + ((wwp + 3) % 96);
            dtok_[rt][q] = dtok;
            float s = 0.f, s2 = 0.f;
            #pragma unroll
            for (int ct = 0; ct < 4; ++ct) {
                const int col = wn * 64 + ct * 16 + l15;
                const float v = acc[rt][ct][q] + proj_b[col] + ALPHA * x[(size_t)dtok * 256 + col];
                acc[rt][ct][q] = v;
                s += v; s2 += v * v;
            }
            s  += __shfl_xor(s, 1, 16);  s += __shfl_xor(s, 2, 16);
            s  += __shfl_xor(s, 4, 16);  s += __shfl_xor(s, 8, 16);
            s2 += __shfl_xor(s2, 1, 16); s2 += __shfl_xor(s2, 2, 16);
            s2 += __shfl_xor(s2, 4, 16); s2 += __shfl_xor(s2, 8, 16);
            if (l15 == 0) { ps[rowl][wn] = s; ps2[rowl][wn] = s2; }
        }
    }
    __syncthreads();
    #pragma unroll
    for (int rt = 0; rt < 4; ++rt) {
        #pragma unroll
        for (int q = 0; q < 4; ++q) {
            const int rowl = wm * 64 + rt * 16 + lg * 4 + q;
            const float S  = ps[rowl][0] + ps[rowl][1] + ps[rowl][2] + ps[rowl][3];
            const float S2 = ps2[rowl][0] + ps2[rowl][1] + ps2[rowl][2] + ps2[rowl][3];
            const float mu = S * (1.0f / 256.0f);
            const float var = S2 * (1.0f / 256.0f) - mu * mu;
            const float rstd = rsqrtf(var + 1e-5f);
            __bf16* op = x1b + (size_t)dtok_[rt][q] * 256;
            #pragma unroll
            for (int ct = 0; ct < 4; ++ct) {
                const int col = wn * 64 + ct * 16 + l15;
                op[col] = (__bf16)((acc[rt][ct][q] - mu) * rstd * n1w[col] + n1b[col]);
            }
        }
    }
}

// ---------------------------------------------------------------------------
// k3f: FUSED MLP fc1+GELU+fc2 + residual + LN2 -> out. hmid lives in LDS.
// Block = 64 rows, 8 waves: row-group rg = wid>>1 (16 rows), half chs = wid&1.
// Wave's x-rows held in registers as 8 A-frags. grid 2304, block 512.
// LDS: w1c 32K + w2c 32K + hs 8K + ps 1K = 73 KB -> 2 blocks/CU.
// ---------------------------------------------------------------------------
__global__ __launch_bounds__(512, 4) void k3f_mlp(
    const __bf16* __restrict__ x1b, const __bf16* __restrict__ w1T,
    const float* __restrict__ fc1_b, const __bf16* __restrict__ w2T,
    const float* __restrict__ fc2_b, const float* __restrict__ n2w,
    const float* __restrict__ n2b, float* __restrict__ out)
{
    __shared__ __attribute__((aligned(16))) __bf16 w1c[64][256];   // 32 KB [hid][k]
    __shared__ __attribute__((aligned(16))) __bf16 w2c[256][64];   // 32 KB [cout][hid]
    __shared__ __attribute__((aligned(16))) __bf16 hs[4][16][64];  // 8 KB
    __shared__ float ps[4][16][2], ps2[4][16][2];                  // 1 KB

    const int t = threadIdx.x;
    const int wid = t >> 6, lane = t & 63;
    const int l15 = lane & 15, lg = lane >> 4;
    const int rg = wid >> 1, chs = wid & 1;
    const int rowbase = blockIdx.x * 64 + rg * 16;

    // x rows -> registers (A-layout fragments, one per K=32 slice)
    bf16x8 af[8];
    #pragma unroll
    for (int kk = 0; kk < 8; ++kk)
        af[kk] = *(const bf16x8*)(x1b + (size_t)(rowbase + l15) * 256 + kk * 32 + lg * 8);

    const f32x4 fzero = {0.f, 0.f, 0.f, 0.f};
    f32x4 acc2[8];
    #pragma unroll
    for (int i = 0; i < 8; ++i) acc2[i] = fzero;

    for (int ch = 0; ch < 16; ++ch) {
        __syncthreads();   // prev chunk's w1c/w2c/hs reads done
        // stage w1c[64][256]: 4 gll x 1KB (2 rows of 512B each)
        #pragma unroll
        for (int i = 0; i < 4; ++i) {
            const int r0 = wid * 8 + i * 2;
            const int row = r0 + (lane >> 5), g = (lane & 31) ^ (row & 7);
            gll16(w1T + (size_t)(ch * 64 + row) * 256 + g * 8, &w1c[r0][0]);
        }
        // stage w2c[256][64]: 4 gll x 1KB (8 rows of 128B each)
        #pragma unroll
        for (int i = 0; i < 4; ++i) {
            const int r0 = wid * 32 + i * 8;
            const int row = r0 + (lane >> 3), g = (lane & 7) ^ (row & 7);
            gll16(w2T + (size_t)row * 1024 + ch * 64 + g * 8, &w2c[r0][0]);
        }
        __syncthreads();

        // fc1: 16 rows x 32 hid (this wave's half of the 64-chunk)
        f32x4 acc1[2];
        acc1[0] = fzero; acc1[1] = fzero;
        #pragma unroll
        for (int kk = 0; kk < 8; ++kk) {
            #pragma unroll
            for (int ct = 0; ct < 2; ++ct) {
                const int br = chs * 32 + ct * 16 + l15;
                const bf16x8 b = *(const bf16x8*)&w1c[br][((kk * 4 + lg) ^ (br & 7)) * 8];
                acc1[ct] = MFMA16(af[kk], b, acc1[ct]);
            }
        }
        // GELU -> hs (row-group slab; swizzled scalar stores)
        #pragma unroll
        for (int ct = 0; ct < 2; ++ct) {
            const int hid = chs * 32 + ct * 16 + l15;
            const float b1 = fc1_b[ch * 64 + hid];
            #pragma unroll
            for (int q = 0; q < 4; ++q) {
                const int row = lg * 4 + q;
                hs[rg][row][(((hid >> 3) ^ (row & 7)) * 8) + (hid & 7)] =
                    (__bf16)gelu_tanh(acc1[ct][q] + b1);
            }
        }
        __syncthreads();   // hs ready (both halves)

        // fc2: 16 rows x 128 cout (this wave's half), k = 64 hid
        #pragma unroll
        for (int kk = 0; kk < 2; ++kk) {
            const bf16x8 a = *(const bf16x8*)&hs[rg][l15][(((kk * 4 + lg) ^ (l15 & 7))) * 8];
            #pragma unroll
            for (int ct = 0; ct < 8; ++ct) {
                const int br = chs * 128 + ct * 16 + l15;
                const bf16x8 b = *(const bf16x8*)&w2c[br][((kk * 4 + lg) ^ (br & 7)) * 8];
                acc2[ct] = MFMA16(a, b, acc2[ct]);
            }
        }
    }

    // epilogue: bias + residual + LN2 (cross-half partials via LDS)
    #pragma unroll
    for (int q = 0; q < 4; ++q) {
        const int row = lg * 4 + q;
        const size_t tok = (size_t)(rowbase + row);
        float s = 0.f, s2 = 0.f;
        #pragma unroll
        for (int ct = 0; ct < 8; ++ct) {
            const int col = chs * 128 + ct * 16 + l15;
            const float v = acc2[ct][q] + fc2_b[col] + ALPHA * (float)x1b[tok * 256 + col];
            acc2[ct][q] = v;
            s += v; s2 += v * v;
        }
        s  += __shfl_xor(s, 1, 16);  s += __shfl_xor(s, 2, 16);
        s  += __shfl_xor(s, 4, 16);  s += __shfl_xor(s, 8, 16);
        s2 += __shfl_xor(s2, 1, 16); s2 += __shfl_xor(s2, 2, 16);
        s2 += __shfl_xor(s2, 4, 16); s2 += __shfl_xor(s2, 8, 16);
        if (l15 == 0) { ps[rg][row][chs] = s; ps2[rg][row][chs] = s2; }
    }
    __syncthreads();
    #pragma unroll
    for (int q = 0; q < 4; ++q) {
        const int row = lg * 4 + q;
        const size_t tok = (size_t)(rowbase + row);
        const float S  = ps[rg][row][0] + ps[rg][row][1];
        const float S2 = ps2[rg][row][0] + ps2[rg][row][1];
        const float mu = S * (1.0f / 256.0f);
        const float var = S2 * (1.0f / 256.0f) - mu * mu;
        const float rstd = rsqrtf(var + 1e-5f);
        float* op = out + tok * 256;
        #pragma unroll
        for (int ct = 0; ct < 8; ++ct) {
            const int col = chs * 128 + ct * 16 + l15;
            op[col] = (acc2[ct][q] - mu) * rstd * n2w[col] + n2b[col];
        }
    }
}

// ---------------------------------------------------------------------------
extern "C" void kernel_launch(void* const* d_in, const int* in_sizes, int n_in,
                              void* d_out, int out_size, void* d_ws, size_t ws_size,
                              hipStream_t stream)
{
    const float* x          = (const float*)d_in[0];
    const float* qkv_w      = (const float*)d_in[1];
    const float* qkv_b      = (const float*)d_in[2];
    const float* bias_table = (const float*)d_in[3];
    const float* proj_w     = (const float*)d_in[4];
    const float* proj_b     = (const float*)d_in[5];
    const float* n1w        = (const float*)d_in[6];
    const float* n1b        = (const float*)d_in[7];
    const float* n2w        = (const float*)d_in[8];
    const float* n2b        = (const float*)d_in[9];
    const float* fc1_w      = (const float*)d_in[10];
    const float* fc1_b      = (const float*)d_in[11];
    const float* fc2_w      = (const float*)d_in[12];
    const float* fc2_b      = (const float*)d_in[13];
    float* out = (float*)d_out;

    // ws layout (bytes), total ~152.6 MB (hmid eliminated):
    //   [0,          75497472)  x1b bf16
    //   [75497472,  150994944)  attnout bf16
    //   [150994944, 152567808)  weight tables
    char* ws = (char*)d_ws;
    __bf16* x1b     = (__bf16*)ws;
    __bf16* attnout = (__bf16*)(ws + 75497472);
    __bf16* qkvT    = (__bf16*)(ws + 150994944);
    __bf16* projT   = (__bf16*)(ws + 151388160);
    __bf16* w1T     = (__bf16*)(ws + 151519232);
    __bf16* w2T     = (__bf16*)(ws + 152043520);

    k0_prep<<<3072, 256, 0, stream>>>(qkv_w, proj_w, fc1_w, fc2_w, qkvT, projT, w1T, w2T);
    k1f_qkv_attn<<<4096, 512, 0, stream>>>(x, qkvT, qkv_b, bias_table, attnout);
    k2_proj_ln<<<1152, 512, 0, stream>>>(attnout, projT, proj_b, x, n1w, n1b, x1b);
    k3f_mlp<<<2304, 512, 0, stream>>>(x1b, w1T, fc1_b, w2T, fc2_b, n2w, n2b, out);
}

// Round 9
// 677.388 us; speedup vs baseline: 1.7137x; 1.0082x over previous
//
#include <hip/hip_runtime.h>
#include <math.h>

typedef __bf16 bf16x8 __attribute__((ext_vector_type(8)));
typedef float f32x4 __attribute__((ext_vector_type(4)));

#define NTOK 147456
#define LTOK 9216
#define ALPHA 1.8612097182041991f
#define QSCALE 5.656854249492380196f
#define MFMA16(a,b,c) __builtin_amdgcn_mfma_f32_16x16x32_bf16((a),(b),(c),0,0,0)
#define SWB(row,kb) ((kb) ^ ((row)&7))

__device__ __forceinline__ float gelu_sig(float x) {
    // sigmoid-form GELU: x * sigma(1.702 x); |err vs erf-GELU| < ~0.02
    const float e = __expf(-1.702f * x);
    return x * __builtin_amdgcn_rcpf(1.0f + e);
}

// async global->LDS, 16B per lane; LDS dest = wave-uniform base + lane*16
__device__ __forceinline__ void gll16(const void* g, void* l) {
    __builtin_amdgcn_global_load_lds(
        (const __attribute__((address_space(1))) void*)g,
        (__attribute__((address_space(3))) void*)l, 16, 0, 0);
}

// ---------------------------------------------------------------------------
// k0: weights -> bf16 transposed [out][k]
// ---------------------------------------------------------------------------
__global__ __launch_bounds__(256) void k0_prep(
    const float* __restrict__ qkv_w, const float* __restrict__ proj_w,
    const float* __restrict__ fc1_w, const float* __restrict__ fc2_w,
    __bf16* __restrict__ qkvT, __bf16* __restrict__ projT,
    __bf16* __restrict__ w1T, __bf16* __restrict__ w2T)
{
    const int id = blockIdx.x * 256 + threadIdx.x;
    if (id < 196608) {
        const int o = id >> 8, k = id & 255;
        qkvT[id] = (__bf16)qkv_w[k * 768 + o];
    } else if (id < 262144) {
        const int i = id - 196608, o = i >> 8, k = i & 255;
        projT[i] = (__bf16)proj_w[k * 256 + o];
    } else if (id < 524288) {
        const int i = id - 262144, o = i >> 8, k = i & 255;
        w1T[i] = (__bf16)fc1_w[k * 1024 + o];
    } else {
        const int i = id - 524288, o = i >> 10, k = i & 1023;
        w2T[i] = (__bf16)fc2_w[k * 256 + o];
    }
}

// ---------------------------------------------------------------------------
// k1f: fused QKV GEMM + attention (unchanged from round 7/8).
// ---------------------------------------------------------------------------
__global__ __launch_bounds__(512, 4) void k1f_qkv_attn(
    const float* __restrict__ x, const __bf16* __restrict__ qkvT,
    const float* __restrict__ qkv_b, const float* __restrict__ bias_table,
    __bf16* __restrict__ attnout)
{
    __shared__ __attribute__((aligned(16))) char SM[81920];
    typedef __bf16 (*a256_t)[256];
    typedef __bf16 (*b32_t)[32];
    typedef __bf16 (*s64_t)[64];
    a256_t As = (a256_t)SM;
    b32_t  Bs = (b32_t)(SM + 24576);
    int* srcrow = (int*)(SM + 73728);

    const int t = threadIdx.x;
    const int wid = t >> 6, lane = t & 63;
    const int l15 = lane & 15, lg = lane >> 4;
    const int blk = blockIdx.x;
    const int win = blk & 255;
    const int wh = win >> 4, ww = win & 15;
    const int h = wid;

    if (t < 48) {
        int n = t; if (n > 35) n = 35;
        const int b = blk >> 8;
        const int gh = (wh * 6 + n / 6 + 3) % 96;
        const int gw = (ww * 6 + n % 6 + 3) % 96;
        srcrow[t] = b * LTOK + gh * 96 + gw;
    }
    __syncthreads();

    for (int o = t; o < 48 * 32; o += 512) {
        const int row = o >> 5, kb = o & 31;
        const float* src = x + (size_t)srcrow[row] * 256 + kb * 8;
        const float4 f0 = *(const float4*)src;
        const float4 f1 = *(const float4*)(src + 4);
        bf16x8 p;
        p[0] = (__bf16)f0.x; p[1] = (__bf16)f0.y; p[2] = (__bf16)f0.z; p[3] = (__bf16)f0.w;
        p[4] = (__bf16)f1.x; p[5] = (__bf16)f1.y; p[6] = (__bf16)f1.z; p[7] = (__bf16)f1.w;
        *(bf16x8*)&As[row][SWB(row, kb) * 8] = p;
    }

    const f32x4 fzero = {0.f, 0.f, 0.f, 0.f};
    f32x4 acc[3][3][2];
    #pragma unroll
    for (int nb = 0; nb < 3; ++nb)
        #pragma unroll
        for (int i = 0; i < 3; ++i)
            #pragma unroll
            for (int j = 0; j < 2; ++j) acc[nb][i][j] = fzero;

    for (int kc = 0; kc < 8; ++kc) {
        __syncthreads();
        #pragma unroll
        for (int i = 0; i < 6; ++i) {
            const int r0 = wid * 96 + i * 16;
            const int row = r0 + (lane >> 2), kbl = lane & 3;
            gll16(qkvT + (size_t)row * 256 + kc * 32 + ((kbl ^ (row & 3)) * 8),
                  &Bs[r0][0]);
        }
        __syncthreads();
        bf16x8 af[3];
        #pragma unroll
        for (int rt = 0; rt < 3; ++rt) {
            const int ar = rt * 16 + l15;
            const int kb = kc * 4 + lg;
            af[rt] = *(const bf16x8*)&As[ar][SWB(ar, kb) * 8];
        }
        #pragma unroll
        for (int nb = 0; nb < 3; ++nb)
            #pragma unroll
            for (int ct = 0; ct < 2; ++ct) {
                const int br = nb * 256 + h * 32 + ct * 16 + l15;
                const bf16x8 bfr = *(const bf16x8*)&Bs[br][((lg ^ (br & 3))) * 8];
                #pragma unroll
                for (int rt = 0; rt < 3; ++rt)
                    acc[nb][rt][ct] = MFMA16(af[rt], bfr, acc[nb][rt][ct]);
            }
    }
    __syncthreads();

    s64_t slab = (s64_t)(SM + wid * 10240);
    s64_t vT   = (s64_t)(SM + wid * 10240 + 6144);
    const size_t rowbase = (size_t)blk * 36;

    int i2_[3], j2_[3], g2_[3];
    #pragma unroll
    for (int ct = 0; ct < 3; ++ct) {
        const int m = ct * 16 + l15;
        const int mm = m < 36 ? m : 35;
        i2_[ct] = mm / 6; j2_[ct] = mm - i2_[ct] * 6;
        const int hg = (wh < 15) ? 0 : (i2_[ct] < 3 ? 1 : 2);
        const int wg = (ww < 15) ? 0 : (j2_[ct] < 3 ? 1 : 2);
        g2_[ct] = hg * 3 + wg;
    }

    #pragma unroll
    for (int ct = 0; ct < 2; ++ct) {
        const int dq = ct * 16 + l15;
        const float qb  = qkv_b[h * 32 + dq];
        const float kb2 = qkv_b[256 + h * 32 + dq];
        #pragma unroll
        for (int rt = 0; rt < 3; ++rt)
            #pragma unroll
            for (int q = 0; q < 4; ++q) {
                const int tok = rt * 16 + lg * 4 + q;
                const int c = (((dq >> 3) ^ (tok & 3)) * 8) + (dq & 7);
                slab[tok][c]      = (__bf16)((acc[0][rt][ct][q] + qb) * QSCALE);
                slab[tok][32 + c] = (__bf16)(acc[1][rt][ct][q] + kb2);
            }
    }

    bf16x8 aq[3], bk[3];
    #pragma unroll
    for (int rt = 0; rt < 3; ++rt) {
        const int ar = rt * 16 + l15;
        aq[rt] = *(const bf16x8*)&slab[ar][((lg ^ (ar & 3))) * 8];
        bk[rt] = *(const bf16x8*)&slab[ar][32 + ((lg ^ (ar & 3))) * 8];
    }
    f32x4 s[3][3];
    #pragma unroll
    for (int rt = 0; rt < 3; ++rt)
        #pragma unroll
        for (int ct = 0; ct < 3; ++ct)
            s[rt][ct] = MFMA16(aq[rt], bk[ct], fzero);

    float inv_[3][4];
    #pragma unroll
    for (int rt = 0; rt < 3; ++rt) {
        #pragma unroll
        for (int q = 0; q < 4; ++q) {
            const int n0 = rt * 16 + lg * 4 + q;
            const int nn = n0 < 36 ? n0 : 35;
            const int i1 = nn / 6, j1 = nn - i1 * 6;
            const int hg1 = (wh < 15) ? 0 : (i1 < 3 ? 1 : 2);
            const int wg1 = (ww < 15) ? 0 : (j1 < 3 ? 1 : 2);
            const int g1 = hg1 * 3 + wg1;
            #pragma unroll
            for (int ct = 0; ct < 3; ++ct) {
                const int m = ct * 16 + l15;
                float val;
                if (m < 36) {
                    val = s[rt][ct][q] + bias_table[((i1 - i2_[ct] + 5) * 11 + (j1 - j2_[ct] + 5)) * 8 + h];
                    if (g1 != g2_[ct]) val -= 100.0f;
                } else {
                    val = -1e30f;
                }
                s[rt][ct][q] = val;
            }
            float mx = fmaxf(fmaxf(s[rt][0][q], s[rt][1][q]), s[rt][2][q]);
            mx = fmaxf(mx, __shfl_xor(mx, 1, 16));
            mx = fmaxf(mx, __shfl_xor(mx, 2, 16));
            mx = fmaxf(mx, __shfl_xor(mx, 4, 16));
            mx = fmaxf(mx, __shfl_xor(mx, 8, 16));
            float sum = 0.f;
            #pragma unroll
            for (int ct = 0; ct < 3; ++ct) {
                const float e = __expf(s[rt][ct][q] - mx);
                s[rt][ct][q] = e;
                sum += e;
            }
            sum += __shfl_xor(sum, 1, 16);
            sum += __shfl_xor(sum, 2, 16);
            sum += __shfl_xor(sum, 4, 16);
            sum += __shfl_xor(sum, 8, 16);
            inv_[rt][q] = 1.0f / sum;
        }
    }

    #pragma unroll
    for (int rt = 0; rt < 3; ++rt)
        #pragma unroll
        for (int q = 0; q < 4; ++q) {
            const int row = rt * 16 + lg * 4 + q;
            #pragma unroll
            for (int ct = 0; ct < 3; ++ct) {
                const int m = ct * 16 + l15;
                slab[row][(((m >> 3) ^ (row & 7)) * 8) + (m & 7)] = (__bf16)s[rt][ct][q];
            }
            const int mz = 48 + l15;
            slab[row][(((mz >> 3) ^ (row & 7)) * 8) + (mz & 7)] = (__bf16)0.0f;
        }

    #pragma unroll
    for (int ct = 0; ct < 2; ++ct) {
        const int d = ct * 16 + l15;
        const float vb = qkv_b[512 + h * 32 + d];
        #pragma unroll
        for (int rt = 0; rt < 3; ++rt)
            #pragma unroll
            for (int q = 0; q < 4; ++q) {
                const int m = rt * 16 + lg * 4 + q;
                vT[d][(((m >> 3) ^ (d & 7)) * 8) + (m & 7)] = (__bf16)(acc[2][rt][ct][q] + vb);
            }
    }
    for (int z = lane; z < 512; z += 64) {
        const int d = z >> 4, m = 48 + (z & 15);
        vT[d][(((m >> 3) ^ (d & 7)) * 8) + (m & 7)] = (__bf16)0.0f;
    }

    f32x4 ov[3][2];
    #pragma unroll
    for (int rt = 0; rt < 3; ++rt)
        #pragma unroll
        for (int cd = 0; cd < 2; ++cd) ov[rt][cd] = fzero;
    #pragma unroll
    for (int kk = 0; kk < 2; ++kk) {
        bf16x8 pa[3], bv[2];
        #pragma unroll
        for (int rt = 0; rt < 3; ++rt) {
            const int ar = rt * 16 + l15;
            pa[rt] = *(const bf16x8*)&slab[ar][(((kk * 4 + lg) ^ (ar & 7))) * 8];
        }
        #pragma unroll
        for (int cd = 0; cd < 2; ++cd) {
            const int d = cd * 16 + l15;
            bv[cd] = *(const bf16x8*)&vT[d][(((kk * 4 + lg) ^ (d & 7))) * 8];
        }
        #pragma unroll
        for (int rt = 0; rt < 3; ++rt)
            #pragma unroll
            for (int cd = 0; cd < 2; ++cd)
                ov[rt][cd] = MFMA16(pa[rt], bv[cd], ov[rt][cd]);
    }

    #pragma unroll
    for (int rt = 0; rt < 3; ++rt)
        #pragma unroll
        for (int cd = 0; cd < 2; ++cd)
            #pragma unroll
            for (int q = 0; q < 4; ++q) {
                const int n = rt * 16 + lg * 4 + q;
                if (n < 36)
                    attnout[(rowbase + n) * 256 + h * 32 + cd * 16 + l15] =
                        (__bf16)(ov[rt][cd][q] * inv_[rt][q]);
            }
}

// ---------------------------------------------------------------------------
// k2: MFMA proj + roll permute + residual + LN1 -> x1b (bf16). Unchanged.
// ---------------------------------------------------------------------------
__global__ __launch_bounds__(512) void k2_proj_ln(
    const __bf16* __restrict__ attnout, const __bf16* __restrict__ projT,
    const float* __restrict__ proj_b, const float* __restrict__ x,
    const float* __restrict__ n1w, const float* __restrict__ n1b,
    __bf16* __restrict__ x1b)
{
    __shared__ __attribute__((aligned(16))) __bf16 As[128][64];
    __shared__ __attribute__((aligned(16))) __bf16 Bs[256][64];
    __shared__ float ps[128][4], ps2[128][4];
    const int t = threadIdx.x;
    const int wid = t >> 6, lane = t & 63;
    const int l15 = lane & 15, lg = lane >> 4;
    const int mb = blockIdx.x;
    const int wm = wid >> 2, wn = wid & 3;

    const f32x4 fzero = {0.f, 0.f, 0.f, 0.f};
    f32x4 acc[4][4];
    #pragma unroll
    for (int i = 0; i < 4; ++i)
        #pragma unroll
        for (int j = 0; j < 4; ++j) acc[i][j] = fzero;

    for (int kc = 0; kc < 4; ++kc) {
        __syncthreads();
        #pragma unroll
        for (int i = 0; i < 2; ++i) {
            const int r0 = wid * 16 + i * 8;
            const int row = r0 + (lane >> 3), kbl = lane & 7;
            gll16(attnout + (size_t)(mb * 128 + row) * 256 + kc * 64 + ((kbl ^ (row & 7)) * 8),
                  &As[r0][0]);
        }
        #pragma unroll
        for (int i = 0; i < 4; ++i) {
            const int r0 = wid * 32 + i * 8;
            const int row = r0 + (lane >> 3), kbl = lane & 7;
            gll16(projT + (size_t)row * 256 + kc * 64 + ((kbl ^ (row & 7)) * 8),
                  &Bs[r0][0]);
        }
        __syncthreads();
        #pragma unroll
        for (int kk = 0; kk < 2; ++kk) {
            bf16x8 af[4], bfr[4];
            #pragma unroll
            for (int rt = 0; rt < 4; ++rt) {
                const int ar = wm * 64 + rt * 16 + l15;
                af[rt] = *(const bf16x8*)&As[ar][((kk * 4 + lg) ^ (ar & 7)) * 8];
            }
            #pragma unroll
            for (int ct = 0; ct < 4; ++ct) {
                const int br = wn * 64 + ct * 16 + l15;
                bfr[ct] = *(const bf16x8*)&Bs[br][((kk * 4 + lg) ^ (br & 7)) * 8];
            }
            #pragma unroll
            for (int rt = 0; rt < 4; ++rt)
                #pragma unroll
                for (int ct = 0; ct < 4; ++ct)
                    acc[rt][ct] = MFMA16(af[rt], bfr[ct], acc[rt][ct]);
        }
    }

    int dtok_[4][4];
    #pragma unroll
    for (int rt = 0; rt < 4; ++rt) {
        #pragma unroll
        for (int q = 0; q < 4; ++q) {
            const int rowl = wm * 64 + rt * 16 + lg * 4 + q;
            const int tok = mb * 128 + rowl;
            const int b = tok / LTOK, l = tok % LTOK;
            const int hh = l / 96, wwp = l % 96;
            const int dtok = b * LTOK + ((hh + 3) % 96) * 96 + ((wwp + 3) % 96);
            dtok_[rt][q] = dtok;
            float s = 0.f, s2 = 0.f;
            #pragma unroll
            for (int ct = 0; ct < 4; ++ct) {
                const int col = wn * 64 + ct * 16 + l15;
                const float v = acc[rt][ct][q] + proj_b[col] + ALPHA * x[(size_t)dtok * 256 + col];
                acc[rt][ct][q] = v;
                s += v; s2 += v * v;
            }
            s  += __shfl_xor(s, 1, 16);  s += __shfl_xor(s, 2, 16);
            s  += __shfl_xor(s, 4, 16);  s += __shfl_xor(s, 8, 16);
            s2 += __shfl_xor(s2, 1, 16); s2 += __shfl_xor(s2, 2, 16);
            s2 += __shfl_xor(s2, 4, 16); s2 += __shfl_xor(s2, 8, 16);
            if (l15 == 0) { ps[rowl][wn] = s; ps2[rowl][wn] = s2; }
        }
    }
    __syncthreads();
    #pragma unroll
    for (int rt = 0; rt < 4; ++rt) {
        #pragma unroll
        for (int q = 0; q < 4; ++q) {
            const int rowl = wm * 64 + rt * 16 + lg * 4 + q;
            const float S  = ps[rowl][0] + ps[rowl][1] + ps[rowl][2] + ps[rowl][3];
            const float S2 = ps2[rowl][0] + ps2[rowl][1] + ps2[rowl][2] + ps2[rowl][3];
            const float mu = S * (1.0f / 256.0f);
            const float var = S2 * (1.0f / 256.0f) - mu * mu;
            const float rstd = rsqrtf(var + 1e-5f);
            __bf16* op = x1b + (size_t)dtok_[rt][q] * 256;
            #pragma unroll
            for (int ct = 0; ct < 4; ++ct) {
                const int col = wn * 64 + ct * 16 + l15;
                op[col] = (__bf16)((acc[rt][ct][q] - mu) * rstd * n1w[col] + n1b[col]);
            }
        }
    }
}

// ---------------------------------------------------------------------------
// k3f v2: fused MLP, 32 rows/wave, double-buffered weights, raw barriers.
// Block = 128 rows, 8 waves = 4 rg x 2 chs. grid 1152, block 512.
// LDS: w1c 2x32K + w2c 2x32K + hs[128][72] 18K + ps 2K = 148K -> 1 block/CU.
// ---------------------------------------------------------------------------
__global__ __launch_bounds__(512, 2) void k3f_mlp(
    const __bf16* __restrict__ x1b, const __bf16* __restrict__ w1T,
    const float* __restrict__ fc1_b, const __bf16* __restrict__ w2T,
    const float* __restrict__ fc2_b, const float* __restrict__ n2w,
    const float* __restrict__ n2b, float* __restrict__ out)
{
    __shared__ __attribute__((aligned(16))) __bf16 w1c[2][64][256];  // 64 KB
    __shared__ __attribute__((aligned(16))) __bf16 w2c[2][256][64];  // 64 KB
    __shared__ __attribute__((aligned(16))) __bf16 hs[128][72];      // 18 KB padded
    __shared__ float ps[128][2], ps2[128][2];                        // 2 KB

    const int t = threadIdx.x;
    const int wid = t >> 6, lane = t & 63;
    const int l15 = lane & 15, lg = lane >> 4;
    const int rg = wid >> 1, chs = wid & 1;
    const int rowbase = blockIdx.x * 128 + rg * 32;

    // persistent A fragments: 32 rows x 256 k (64 VGPR)
    bf16x8 af[2][8];
    #pragma unroll
    for (int rt = 0; rt < 2; ++rt)
        #pragma unroll
        for (int kk = 0; kk < 8; ++kk)
            af[rt][kk] = *(const bf16x8*)(x1b + (size_t)(rowbase + rt * 16 + l15) * 256 + kk * 32 + lg * 8);

    const f32x4 fzero = {0.f, 0.f, 0.f, 0.f};
    f32x4 acc2[2][8];
    #pragma unroll
    for (int i = 0; i < 2; ++i)
        #pragma unroll
        for (int j = 0; j < 8; ++j) acc2[i][j] = fzero;

    // stage chunk c into buffer b (8 x 1KB gll per wave)
    #define STAGE_W(b, c)                                                       \
    {                                                                           \
        _Pragma("unroll")                                                       \
        for (int i = 0; i < 4; ++i) {                                           \
            const int r0 = wid * 8 + i * 2;                                     \
            const int row = r0 + (lane >> 5);                                   \
            const int g = (lane & 31) ^ (row & 7);                              \
            gll16(w1T + (size_t)((c) * 64 + row) * 256 + g * 8, &w1c[b][r0][0]);\
        }                                                                       \
        _Pragma("unroll")                                                       \
        for (int i = 0; i < 4; ++i) {                                           \
            const int r0 = wid * 32 + i * 8;                                    \
            const int row = r0 + (lane >> 3);                                   \
            const int g = (lane & 7) ^ (row & 7);                               \
            gll16(w2T + (size_t)row * 1024 + (c) * 64 + g * 8, &w2c[b][r0][0]); \
        }                                                                       \
    }

    STAGE_W(0, 0);
    __syncthreads();   // full drain: chunk 0 staged

    for (int ch = 0; ch < 16; ++ch) {
        const int cur = ch & 1;
        if (ch < 15) STAGE_W(cur ^ 1, ch + 1);   // prefetch next chunk (in flight)

        // ---- fc1: 32 rows x 32 hid (this wave's chs half) ----
        f32x4 acc1[2][2];
        #pragma unroll
        for (int i = 0; i < 2; ++i)
            #pragma unroll
            for (int j = 0; j < 2; ++j) acc1[i][j] = fzero;
        #pragma unroll
        for (int kk = 0; kk < 8; ++kk) {
            #pragma unroll
            for (int ct = 0; ct < 2; ++ct) {
                const int br = chs * 32 + ct * 16 + l15;
                const bf16x8 b = *(const bf16x8*)&w1c[cur][br][((kk * 4 + lg) ^ (br & 7)) * 8];
                #pragma unroll
                for (int rt = 0; rt < 2; ++rt)
                    acc1[rt][ct] = MFMA16(af[rt][kk], b, acc1[rt][ct]);
            }
        }
        // GELU -> hs (padded rows; ~2-way conflicts)
        #pragma unroll
        for (int ct = 0; ct < 2; ++ct) {
            const int hid = chs * 32 + ct * 16 + l15;
            const float b1v = fc1_b[ch * 64 + hid];
            #pragma unroll
            for (int rt = 0; rt < 2; ++rt)
                #pragma unroll
                for (int q = 0; q < 4; ++q) {
                    const int lrow = rt * 16 + lg * 4 + q;
                    hs[rg * 32 + lrow][((hid >> 3) ^ (lrow & 7)) * 8 + (hid & 7)] =
                        (__bf16)gelu_sig(acc1[rt][ct][q] + b1v);
                }
        }
        // hs ready: drain LDS only (keep gll prefetch in flight), raw barrier
        asm volatile("s_waitcnt lgkmcnt(0)" ::: "memory");
        __builtin_amdgcn_sched_barrier(0);
        __builtin_amdgcn_s_barrier();
        __builtin_amdgcn_sched_barrier(0);

        // ---- fc2: 32 rows x 128 cout (this wave's chs half), k = 64 hid ----
        #pragma unroll
        for (int kk2 = 0; kk2 < 2; ++kk2) {
            bf16x8 a[2];
            #pragma unroll
            for (int rt = 0; rt < 2; ++rt) {
                const int grow = rg * 32 + rt * 16 + l15;
                a[rt] = *(const bf16x8*)&hs[grow][((kk2 * 4 + lg) ^ (l15 & 7)) * 8];
            }
            #pragma unroll
            for (int ct = 0; ct < 8; ++ct) {
                const int br = chs * 128 + ct * 16 + l15;
                const bf16x8 b = *(const bf16x8*)&w2c[cur][br][((kk2 * 4 + lg) ^ (br & 7)) * 8];
                #pragma unroll
                for (int rt = 0; rt < 2; ++rt)
                    acc2[rt][ct] = MFMA16(a[rt], b, acc2[rt][ct]);
            }
        }

        // end of chunk: prefetch landed + everyone done reading cur; raw barrier
        asm volatile("s_waitcnt vmcnt(0) lgkmcnt(0)" ::: "memory");
        __builtin_amdgcn_sched_barrier(0);
        __builtin_amdgcn_s_barrier();
        __builtin_amdgcn_sched_barrier(0);
    }

    // ---- epilogue: bias + residual + LN2 ----
    #pragma unroll
    for (int rt = 0; rt < 2; ++rt) {
        #pragma unroll
        for (int q = 0; q < 4; ++q) {
            const int lrow = rt * 16 + lg * 4 + q;
            const int grow = rg * 32 + lrow;
            const size_t tok = (size_t)(blockIdx.x * 128 + grow);
            float s = 0.f, s2 = 0.f;
            #pragma unroll
            for (int ct = 0; ct < 8; ++ct) {
                const int col = chs * 128 + ct * 16 + l15;
                const float v = acc2[rt][ct][q] + fc2_b[col] + ALPHA * (float)x1b[tok * 256 + col];
                acc2[rt][ct][q] = v;
                s += v; s2 += v * v;
            }
            s  += __shfl_xor(s, 1, 16);  s += __shfl_xor(s, 2, 16);
            s  += __shfl_xor(s, 4, 16);  s += __shfl_xor(s, 8, 16);
            s2 += __shfl_xor(s2, 1, 16); s2 += __shfl_xor(s2, 2, 16);
            s2 += __shfl_xor(s2, 4, 16); s2 += __shfl_xor(s2, 8, 16);
            if (l15 == 0) { ps[grow][chs] = s; ps2[grow][chs] = s2; }
        }
    }
    __syncthreads();
    #pragma unroll
    for (int rt = 0; rt < 2; ++rt) {
        #pragma unroll
        for (int q = 0; q < 4; ++q) {
            const int lrow = rt * 16 + lg * 4 + q;
            const int grow = rg * 32 + lrow;
            const size_t tok = (size_t)(blockIdx.x * 128 + grow);
            const float S  = ps[grow][0] + ps[grow][1];
            const float S2 = ps2[grow][0] + ps2[grow][1];
            const float mu = S * (1.0f / 256.0f);
            const float var = S2 * (1.0f / 256.0f) - mu * mu;
            const float rstd = rsqrtf(var + 1e-5f);
            float* op = out + tok * 256;
            #pragma unroll
            for (int ct = 0; ct < 8; ++ct) {
                const int col = chs * 128 + ct * 16 + l15;
                op[col] = (acc2[rt][ct][q] - mu) * rstd * n2w[col] + n2b[col];
            }
        }
    }
    #undef STAGE_W
}

// ---------------------------------------------------------------------------
extern "C" void kernel_launch(void* const* d_in, const int* in_sizes, int n_in,
                              void* d_out, int out_size, void* d_ws, size_t ws_size,
                              hipStream_t stream)
{
    const float* x          = (const float*)d_in[0];
    const float* qkv_w      = (const float*)d_in[1];
    const float* qkv_b      = (const float*)d_in[2];
    const float* bias_table = (const float*)d_in[3];
    const float* proj_w     = (const float*)d_in[4];
    const float* proj_b     = (const float*)d_in[5];
    const float* n1w        = (const float*)d_in[6];
    const float* n1b        = (const float*)d_in[7];
    const float* n2w        = (const float*)d_in[8];
    const float* n2b        = (const float*)d_in[9];
    const float* fc1_w      = (const float*)d_in[10];
    const float* fc1_b      = (const float*)d_in[11];
    const float* fc2_w      = (const float*)d_in[12];
    const float* fc2_b      = (const float*)d_in[13];
    float* out = (float*)d_out;

    // ws layout (bytes):
    //   [0,          75497472)  x1b bf16
    //   [75497472,  150994944)  attnout bf16
    //   [150994944, 152567808)  weight tables
    char* ws = (char*)d_ws;
    __bf16* x1b     = (__bf16*)ws;
    __bf16* attnout = (__bf16*)(ws + 75497472);
    __bf16* qkvT    = (__bf16*)(ws + 150994944);
    __bf16* projT   = (__bf16*)(ws + 151388160);
    __bf16* w1T     = (__bf16*)(ws + 151519232);
    __bf16* w2T     = (__bf16*)(ws + 152043520);

    k0_prep<<<3072, 256, 0, stream>>>(qkv_w, proj_w, fc1_w, fc2_w, qkvT, projT, w1T, w2T);
    k1f_qkv_attn<<<4096, 512, 0, stream>>>(x, qkvT, qkv_b, bias_table, attnout);
    k2_proj_ln<<<1152, 512, 0, stream>>>(attnout, projT, proj_b, x, n1w, n1b, x1b);
    k3f_mlp<<<1152, 512, 0, stream>>>(x1b, w1T, fc1_b, w2T, fc2_b, n2w, n2b, out);
}